// Round 8
// baseline (682.552 us; speedup 1.0000x reference)
//
#include <hip/hip_runtime.h>
#include <hip/hip_bf16.h>
#include <cmath>

// ---------------------------------------------------------------------------
// RWKV-7 TimeMixing. B=2, T=2048, C=1024, H=16, N=64, M=4096.
// FAST path (ws >= 172MB):
//   - stages 1+2: 256x256-tile 8-wave phase-split MFMA GEMM (T2 swizzle +
//     counted vmcnt pipeline + setprio), global_load_lds staging.
//   - scan inputs r/k/v fp32 from GEMM epilogues (FE_F32/FE_AKF/FE_VBLENDF).
//   - pass1: XCD-sibling swizzle -- the 8 i-split waves of one (bh,c) share
//     blockIdx%8, hence one XCD L2, so redundant r/v re-reads hit L2 not HBM
//     (r7: FETCH 196MB, 8x logical redundancy, 1.55TB/s traffic-bound).
//     pass1 also stores the running decay product cumw[t,i].
//   - pass3: fully parallel (loads cumw instead of recomputing the serial
//     product) -- every t independent, latency hideable.
//   - fused LN + rkv + gate -> bf16, final Wo GEMM (legacy 128^2 kernel)
// Workspace lifetime map (MB offsets):
//   wb 0-20 | w1cat 20-24 | w2cat 24-28 | ax* 28-84 (dead after s1)
//   s1 out: btw 84-100, bt1a 100-108, bt1g 108-116, bt1v 116-124,
//           fr32 124-140 (fp32 r), bk 140-148, bv 148-156 (dead post-s2)
//   s2 out (over dead ax*): bw 28-44, fk32 44-60, fv32 60-76, bg 76-84
//   scan: by 84-100 (over btw), byc 100-116, bE 116-124 (over bt1v),
//         cumw 140-156 (over bk+bv), bDd 156, bS0 160-168
//   ln out: bz 140-148 (over cumw, dead after pass3)
// FALLBACK: round-1 fp32 path, known-good.
// ---------------------------------------------------------------------------

typedef unsigned short u16;
typedef __attribute__((ext_vector_type(8))) short short8;   // 8 x bf16 frag
typedef __attribute__((ext_vector_type(4))) float f32x4;

#define NDIM 1024

__device__ __forceinline__ float sigf(float x) { return 1.f / (1.f + expf(-x)); }
__device__ __forceinline__ u16 f2b(float f) {
    union { float f; unsigned int u; } v; v.f = f;
    unsigned int r = (v.u + 0x7FFFu + ((v.u >> 16) & 1u)) >> 16;
    return (u16)r;
}
__device__ __forceinline__ float b2f(u16 b) {
    union { unsigned int u; float f; } v; v.u = ((unsigned int)b) << 16;
    return v.f;
}
__device__ __forceinline__ float4 b2f4(ushort4 u) {
    return make_float4(b2f(u.x), b2f(u.y), b2f(u.z), b2f(u.w));
}

#define GLD16(gp, lp)                                                         \
    __builtin_amdgcn_global_load_lds(                                         \
        (const __attribute__((address_space(1))) void*)(gp),                  \
        (__attribute__((address_space(3))) void*)(lp), 16, 0, 0)

// counted-vmcnt barrier
#define WAITB(n) do {                                                         \
    asm volatile("s_waitcnt vmcnt(" #n ")" ::: "memory");                     \
    __builtin_amdgcn_s_barrier();                                             \
    asm volatile("" ::: "memory"); } while (0)

// ============================ FAST PATH ====================================

// ---- fused prep: 10 weights->bf16 | W1,W2 cat | token-shift mixes --------
struct PrepArgs {
    const float* wp[10]; u16* wdst;
    const float* W1; const float* W2; u16* c1; u16* c2;
    const float* x;
    const float* tmr; const float* tmw; const float* tmk;
    const float* tmv; const float* tma; const float* tmg;
    u16 *axr, *axk, *axv, *axa, *axg, *axw;
    int T;
};

__global__ __launch_bounds__(256)
void prep_all(PrepArgs a)
{
    const int bid = blockIdx.x;
    const int tid = threadIdx.x;
    if (bid < 10240) {
        const int wi = bid >> 10;
        const int t  = (((bid & 1023) << 8) | tid) << 2;
        const float4 v = *(const float4*)&a.wp[wi][t];
        ushort4 o; o.x = f2b(v.x); o.y = f2b(v.y); o.z = f2b(v.z); o.w = f2b(v.w);
        *(ushort4*)&a.wdst[((size_t)wi << 20) + t] = o;
    } else if (bid < 11264) {
        const int t = ((bid - 10240) * 256 + tid) << 2;
        const int n = t >> 10, c = t & 1023;
        const size_t rb = (size_t)n * 2048 + c;
#pragma unroll
        for (int wsel = 0; wsel < 2; ++wsel) {
            const float* W = wsel ? a.W2 : a.W1;
            u16* dc = wsel ? a.c2 : a.c1;
            const float4 v = *(const float4*)&W[t];
            ushort4 hi;
            hi.x = f2b(v.x); hi.y = f2b(v.y); hi.z = f2b(v.z); hi.w = f2b(v.w);
            *(ushort4*)&dc[rb]        = hi;
            *(ushort4*)&dc[rb + 1024] = hi;
        }
    } else {
        const int t = ((bid - 11264) * 256 + tid) << 2;
        const int m = t >> 10, c = t & 1023;
        const float4 xc = *(const float4*)&a.x[t];
        float4 xp = make_float4(0.f, 0.f, 0.f, 0.f);
        if ((m % a.T) != 0) xp = *(const float4*)&a.x[t - 1024];
        const float4 d = make_float4(xp.x - xc.x, xp.y - xc.y, xp.z - xc.z, xp.w - xc.w);
#define MIX_STORE(tm, dstp)                                            \
    {   const float4 tc = *(const float4*)&tm[c];                      \
        ushort4 o;                                                     \
        o.x = f2b(xc.x + d.x * tc.x); o.y = f2b(xc.y + d.y * tc.y);    \
        o.z = f2b(xc.z + d.z * tc.z); o.w = f2b(xc.w + d.w * tc.w);    \
        *(ushort4*)&dstp[t] = o; }
        MIX_STORE(a.tmr, a.axr) MIX_STORE(a.tmk, a.axk) MIX_STORE(a.tmv, a.axv)
        MIX_STORE(a.tma, a.axa) MIX_STORE(a.tmg, a.axg)
#undef MIX_STORE
        {   // w path: [hi | lo]
            const float4 tc = *(const float4*)&a.tmw[c];
            float4 v = make_float4(xc.x + d.x * tc.x, xc.y + d.y * tc.y,
                                   xc.z + d.z * tc.z, xc.w + d.w * tc.w);
            ushort4 hi, lo;
            hi.x = f2b(v.x); lo.x = f2b(v.x - b2f(hi.x));
            hi.y = f2b(v.y); lo.y = f2b(v.y - b2f(hi.y));
            hi.z = f2b(v.z); lo.z = f2b(v.z - b2f(hi.z));
            hi.w = f2b(v.w); lo.w = f2b(v.w - b2f(hi.w));
            const size_t rb = (size_t)m * 2048 + c;
            *(ushort4*)&a.axw[rb]        = hi;
            *(ushort4*)&a.axw[rb + 1024] = lo;
        }
    }
}

// ---- shared job types -----------------------------------------------------
enum { FE_F32 = 0, FE_B16 = 1, FE_SIGB = 2, FE_TANHCAT = 3, FE_W = 4, FE_AK = 5,
       FE_VBLEND = 6, FE_AKF = 7, FE_VBLENDF = 8 };

struct GemmJob {
    const u16* A; const u16* B; float* Of; u16* Ob;
    const float* bias; const float* extra; int K; int epi;
};
struct GemmBatch { GemmJob j[7]; };

// ===========================================================================
// 256x256-tile 8-wave phase-split NT-GEMM (bf16 MFMA). See r3 notes.
// ===========================================================================
__global__ __launch_bounds__(512, 1)
void mfma_batch8(GemmBatch batch)
{
    __shared__ __align__(16) u16 As[2][256 * 64];
    __shared__ __align__(16) u16 Bs[2][256 * 64];

    const GemmJob job = batch.j[blockIdx.x >> 6];
    const int t6 = blockIdx.x & 63;
    const int mt = ((t6 & 7) << 1) | ((t6 >> 3) & 1);   // 0..15
    const int nt = t6 >> 4;                              // 0..3
    const int m0 = mt << 8, n0 = nt << 8;
    const int K  = job.K;
    const u16* __restrict__ Ag = job.A;
    const u16* __restrict__ Bg = job.B;

    const int tid = threadIdx.x;
    const int wv  = tid >> 6;
    const int wm  = wv >> 2;
    const int wn  = wv & 3;
    const int ln  = tid & 63;
    const int fr  = ln & 15;
    const int fq  = ln >> 4;

    const int rowoff = tid >> 3;
    const int cgoff  = ((tid & 7) ^ (rowoff & 7)) << 3;
    const int wvb    = wv << 9;

    const int c0 = ((fq)     ^ (fr & 7)) << 3;
    const int c1 = ((4 + fq) ^ (fr & 7)) << 3;
    const int aOff0 = (wm * 16 + fr) * 64 + c0;
    const int aOff1 = (wm * 16 + fr) * 64 + c1;
    const int bBase = (wn * 64 + fr) * 64;

    f32x4 acc[8][4];
#pragma unroll
    for (int i = 0; i < 8; ++i)
#pragma unroll
        for (int j = 0; j < 4; ++j) {
            acc[i][j][0] = 0.f; acc[i][j][1] = 0.f; acc[i][j][2] = 0.f; acc[i][j][3] = 0.f;
        }

    auto stage = [&](const u16* __restrict__ G, int row0, u16* lp, int kc) {
        const u16* g0 = G + (size_t)(row0 + rowoff) * K + kc + cgoff;
        GLD16(g0, lp + wvb);
        GLD16(g0 + ((size_t)K << 6), lp + wvb + 4096);
    };

    stage(Bg, n0,       &Bs[0][0],    0);
    stage(Bg, n0 + 128, &Bs[0][8192], 0);
    stage(Ag, m0,       &As[0][0],    0);
    stage(Ag, m0 + 128, &As[0][8192], 0);

    short8 aL[4][2], aH[4][2], bA[2][2], bB[2][2];
    const int NT = K >> 6;
    int cur = 0;

    for (int kt = 0; kt < NT - 1; ++kt) {
        const int kn = (kt + 1) << 6;
        u16* An = &As[cur ^ 1][0];
        u16* Bn = &Bs[cur ^ 1][0];

        WAITB(2);
#pragma unroll
        for (int i = 0; i < 4; ++i) {
            aL[i][0] = *(const short8*)&As[cur][aOff0 + i * 2048];
            aL[i][1] = *(const short8*)&As[cur][aOff1 + i * 2048];
        }
#pragma unroll
        for (int j = 0; j < 2; ++j) {
            bA[j][0] = *(const short8*)&Bs[cur][bBase + j * 1024 + c0];
            bA[j][1] = *(const short8*)&Bs[cur][bBase + j * 1024 + c1];
        }
        stage(Bg, n0, Bn, kn);
        __builtin_amdgcn_s_setprio(1);
#pragma unroll
        for (int i = 0; i < 4; ++i)
#pragma unroll
            for (int j = 0; j < 2; ++j) {
                acc[i][j] = __builtin_amdgcn_mfma_f32_16x16x32_bf16(aL[i][0], bA[j][0], acc[i][j], 0, 0, 0);
                acc[i][j] = __builtin_amdgcn_mfma_f32_16x16x32_bf16(aL[i][1], bA[j][1], acc[i][j], 0, 0, 0);
            }
        __builtin_amdgcn_s_setprio(0);

#pragma unroll
        for (int j = 0; j < 2; ++j) {
            bB[j][0] = *(const short8*)&Bs[cur][bBase + (2 + j) * 1024 + c0];
            bB[j][1] = *(const short8*)&Bs[cur][bBase + (2 + j) * 1024 + c1];
        }
        stage(Bg, n0 + 128, Bn + 8192, kn);
        __builtin_amdgcn_s_setprio(1);
#pragma unroll
        for (int i = 0; i < 4; ++i)
#pragma unroll
            for (int j = 0; j < 2; ++j) {
                acc[i][2 + j] = __builtin_amdgcn_mfma_f32_16x16x32_bf16(aL[i][0], bB[j][0], acc[i][2 + j], 0, 0, 0);
                acc[i][2 + j] = __builtin_amdgcn_mfma_f32_16x16x32_bf16(aL[i][1], bB[j][1], acc[i][2 + j], 0, 0, 0);
            }
        __builtin_amdgcn_s_setprio(0);

        WAITB(4);
#pragma unroll
        for (int i = 0; i < 4; ++i) {
            aH[i][0] = *(const short8*)&As[cur][aOff0 + 8192 + i * 2048];
            aH[i][1] = *(const short8*)&As[cur][aOff1 + 8192 + i * 2048];
        }
        stage(Ag, m0, An, kn);
        __builtin_amdgcn_s_setprio(1);
#pragma unroll
        for (int i = 0; i < 4; ++i)
#pragma unroll
            for (int j = 0; j < 2; ++j) {
                acc[4 + i][j] = __builtin_amdgcn_mfma_f32_16x16x32_bf16(aH[i][0], bA[j][0], acc[4 + i][j], 0, 0, 0);
                acc[4 + i][j] = __builtin_amdgcn_mfma_f32_16x16x32_bf16(aH[i][1], bA[j][1], acc[4 + i][j], 0, 0, 0);
            }
        __builtin_amdgcn_s_setprio(0);

        stage(Ag, m0 + 128, An + 8192, kn);
        __builtin_amdgcn_s_setprio(1);
#pragma unroll
        for (int i = 0; i < 4; ++i)
#pragma unroll
            for (int j = 0; j < 2; ++j) {
                acc[4 + i][2 + j] = __builtin_amdgcn_mfma_f32_16x16x32_bf16(aH[i][0], bB[j][0], acc[4 + i][2 + j], 0, 0, 0);
                acc[4 + i][2 + j] = __builtin_amdgcn_mfma_f32_16x16x32_bf16(aH[i][1], bB[j][1], acc[4 + i][2 + j], 0, 0, 0);
            }
        __builtin_amdgcn_s_setprio(0);
        cur ^= 1;
    }

    WAITB(2);
#pragma unroll
    for (int i = 0; i < 4; ++i) {
        aL[i][0] = *(const short8*)&As[cur][aOff0 + i * 2048];
        aL[i][1] = *(const short8*)&As[cur][aOff1 + i * 2048];
    }
#pragma unroll
    for (int j = 0; j < 2; ++j) {
        bA[j][0] = *(const short8*)&Bs[cur][bBase + j * 1024 + c0];
        bA[j][1] = *(const short8*)&Bs[cur][bBase + j * 1024 + c1];
        bB[j][0] = *(const short8*)&Bs[cur][bBase + (2 + j) * 1024 + c0];
        bB[j][1] = *(const short8*)&Bs[cur][bBase + (2 + j) * 1024 + c1];
    }
    __builtin_amdgcn_s_setprio(1);
#pragma unroll
    for (int i = 0; i < 4; ++i)
#pragma unroll
        for (int j = 0; j < 2; ++j) {
            acc[i][j]     = __builtin_amdgcn_mfma_f32_16x16x32_bf16(aL[i][0], bA[j][0], acc[i][j], 0, 0, 0);
            acc[i][j]     = __builtin_amdgcn_mfma_f32_16x16x32_bf16(aL[i][1], bA[j][1], acc[i][j], 0, 0, 0);
            acc[i][2 + j] = __builtin_amdgcn_mfma_f32_16x16x32_bf16(aL[i][0], bB[j][0], acc[i][2 + j], 0, 0, 0);
            acc[i][2 + j] = __builtin_amdgcn_mfma_f32_16x16x32_bf16(aL[i][1], bB[j][1], acc[i][2 + j], 0, 0, 0);
        }
    __builtin_amdgcn_s_setprio(0);
    WAITB(0);
#pragma unroll
    for (int i = 0; i < 4; ++i) {
        aH[i][0] = *(const short8*)&As[cur][aOff0 + 8192 + i * 2048];
        aH[i][1] = *(const short8*)&As[cur][aOff1 + 8192 + i * 2048];
    }
    __builtin_amdgcn_s_setprio(1);
#pragma unroll
    for (int i = 0; i < 4; ++i)
#pragma unroll
        for (int j = 0; j < 2; ++j) {
            acc[4 + i][j]     = __builtin_amdgcn_mfma_f32_16x16x32_bf16(aH[i][0], bA[j][0], acc[4 + i][j], 0, 0, 0);
            acc[4 + i][j]     = __builtin_amdgcn_mfma_f32_16x16x32_bf16(aH[i][1], bA[j][1], acc[4 + i][j], 0, 0, 0);
            acc[4 + i][2 + j] = __builtin_amdgcn_mfma_f32_16x16x32_bf16(aH[i][0], bB[j][0], acc[4 + i][2 + j], 0, 0, 0);
            acc[4 + i][2 + j] = __builtin_amdgcn_mfma_f32_16x16x32_bf16(aH[i][1], bB[j][1], acc[4 + i][2 + j], 0, 0, 0);
        }
    __builtin_amdgcn_s_setprio(0);

    // ---- C write: epi switch hoisted OUT of the unrolled loops ----
    float* __restrict__ Of = job.Of;
    u16*   __restrict__ Ob = job.Ob;
    const float* bias  = job.bias;
    const float* extra = job.extra;
    const int epi = job.epi;

#define CWRITE(...)                                                           \
    _Pragma("unroll")                                                         \
    for (int i = 0; i < 8; ++i) {                                             \
        _Pragma("unroll")                                                     \
        for (int r = 0; r < 4; ++r) {                                         \
            const int m = m0 + i * 32 + wm * 16 + fq * 4 + r;                 \
            const size_t rowf = (size_t)m * NDIM;                             \
            _Pragma("unroll")                                                 \
            for (int j = 0; j < 4; ++j) {                                     \
                const int n = n0 + wn * 64 + j * 16 + fr;                     \
                const float val = acc[i][j][r];                               \
                __VA_ARGS__;                                                  \
            }                                                                 \
        }                                                                     \
    }

    switch (epi) {
    case FE_F32:
        CWRITE(Of[rowf + n] = val)
        break;
    case FE_B16:
        CWRITE(Ob[rowf + n] = f2b(val))
        break;
    case FE_SIGB:
        CWRITE(Ob[rowf + n] = f2b(sigf(val)))
        break;
    case FE_TANHCAT:
        CWRITE({
            const float tv = tanhf(val);
            const u16 hi = f2b(tv);
            const u16 lo = f2b(tv - b2f(hi));
            const size_t rc = (size_t)m * 2048;
            Ob[rc + n] = hi; Ob[rc + 1024 + n] = lo;
        })
        break;
    case FE_W:
        CWRITE(Of[rowf + n] = expf(-0.606531f * sigf(bias[n] + val)))
        break;
    case FE_AK:
        CWRITE({
            const float kv = b2f(Ob[rowf + n]);
            Ob[rowf + n] = f2b(kv * (1.f + (sigf(bias[n] + val) - 1.f) * extra[n]));
        })
        break;
    case FE_AKF:   // read bf16 k (Ob), write fp32 (Of)
        CWRITE({
            const float kv = b2f(Ob[rowf + n]);
            Of[rowf + n] = kv * (1.f + (sigf(bias[n] + val) - 1.f) * extra[n]);
        })
        break;
    case FE_VBLENDF: // read bf16 v (Ob) + fp32 v_first (extra), write fp32
        CWRITE({
            const float vv = b2f(Ob[rowf + n]);
            const float s  = sigf(bias[n] + val);
            Of[rowf + n] = vv + (extra[rowf + n] - vv) * s;
        })
        break;
    default: // FE_VBLEND
        CWRITE({
            const float vv = b2f(Ob[rowf + n]);
            const float s  = sigf(bias[n] + val);
            Ob[rowf + n] = f2b(vv + (extra[rowf + n] - vv) * s);
        })
        break;
    }
#undef CWRITE
}

// ---- legacy 128x128 MFMA kernel (kept for stage-3's small grid) ----------
#define TKt 32

__global__ __launch_bounds__(256)
void mfma_batch(GemmBatch batch)
{
    __shared__ u16 As[2][128 * 32];
    __shared__ u16 Bs[2][128 * 32];
    const GemmJob job = batch.j[blockIdx.x >> 8];
    const int bid = blockIdx.x & 255;
    const int m0 = (((bid & 7) << 2) + ((bid >> 3) & 3)) << 7;
    const int n0 = (bid >> 5) << 7;
    const int K  = job.K;
    const u16* __restrict__ Ag = job.A;
    const u16* __restrict__ Bg = job.B;

    const int t  = threadIdx.x;
    const int wv = t >> 6, ln = t & 63;
    const int wr = (wv >> 1) * 64;
    const int wc = (wv & 1) * 64;
    const int fr = ln & 15;
    const int fq = ln >> 4;
    const int lrow = ln >> 2;
    const int lcol = (ln & 3) << 3;

    f32x4 acc[4][4];
#pragma unroll
    for (int i = 0; i < 4; ++i)
#pragma unroll
        for (int j = 0; j < 4; ++j) {
            acc[i][j][0] = 0.f; acc[i][j][1] = 0.f; acc[i][j][2] = 0.f; acc[i][j][3] = 0.f;
        }

    const int slab0 = (wv << 4);
    const int slab1 = 64 + (wv << 4);

    auto issue = [&](int k0, int buf) {
        const size_t ga0 = (size_t)(m0 + slab0 + lrow) * K + k0 + lcol;
        const size_t ga1 = (size_t)(m0 + slab1 + lrow) * K + k0 + lcol;
        const size_t gb0 = (size_t)(n0 + slab0 + lrow) * K + k0 + lcol;
        const size_t gb1 = (size_t)(n0 + slab1 + lrow) * K + k0 + lcol;
        GLD16(Ag + ga0, &As[buf][slab0 * 32]);
        GLD16(Ag + ga1, &As[buf][slab1 * 32]);
        GLD16(Bg + gb0, &Bs[buf][slab0 * 32]);
        GLD16(Bg + gb1, &Bs[buf][slab1 * 32]);
    };

    issue(0, 0);
    const int NT = K / TKt;
    int cur = 0;
    for (int it = 0; it < NT; ++it) {
        __syncthreads();
        if (it + 1 < NT) issue((it + 1) * TKt, cur ^ 1);
        short8 af[4], bfr[4];
#pragma unroll
        for (int i = 0; i < 4; ++i) {
            af[i]  = *(const short8*)&As[cur][(wr + i * 16 + fr) * 32 + fq * 8];
            bfr[i] = *(const short8*)&Bs[cur][(wc + i * 16 + fr) * 32 + fq * 8];
        }
#pragma unroll
        for (int i = 0; i < 4; ++i)
#pragma unroll
            for (int j = 0; j < 4; ++j)
                acc[i][j] = __builtin_amdgcn_mfma_f32_16x16x32_bf16(af[i], bfr[j], acc[i][j], 0, 0, 0);
        cur ^= 1;
    }

    float* __restrict__ Of = job.Of;
    u16*   __restrict__ Ob = job.Ob;
    const float* bias  = job.bias;
    const float* extra = job.extra;
    const int epi = job.epi;

#pragma unroll
    for (int i = 0; i < 4; ++i) {
#pragma unroll
        for (int r = 0; r < 4; ++r) {
            const int m = m0 + wr + i * 16 + fq * 4 + r;
            const size_t rowf = (size_t)m * NDIM;
#pragma unroll
            for (int j = 0; j < 4; ++j) {
                const int n = n0 + wc + j * 16 + fr;
                const float val = acc[i][j][r];
                switch (epi) {
                case FE_F32:
                    Of[rowf + n] = val; break;
                case FE_B16:
                    Ob[rowf + n] = f2b(val); break;
                case FE_SIGB:
                    Ob[rowf + n] = f2b(sigf(val)); break;
                case FE_TANHCAT: {
                    const float tv = tanhf(val);
                    const u16 hi = f2b(tv);
                    const u16 lo = f2b(tv - b2f(hi));
                    const size_t rc = (size_t)m * 2048;
                    Ob[rc + n] = hi; Ob[rc + 1024 + n] = lo;
                    break; }
                case FE_W:
                    Of[rowf + n] = expf(-0.606531f * sigf(bias[n] + val)); break;
                case FE_AK: {
                    const float kv = b2f(Ob[rowf + n]);
                    Ob[rowf + n] = f2b(kv * (1.f + (sigf(bias[n] + val) - 1.f) * extra[n]));
                    break; }
                default: {
                    const float vv = b2f(Ob[rowf + n]);
                    const float s  = sigf(bias[n] + val);
                    Ob[rowf + n] = f2b(vv + (extra[rowf + n] - vv) * s);
                    break; }
                }
            }
        }
    }
}

// ---- WKV7 chunked scan (fp32 r/k/v inputs) --------------------------------
#define CL 128
#define NC 16

// pass1: zero-start scan per (b,h,chunk,i-split). 8-way j-split, 4-deep
// register prefetch, fp32. XCD-sibling swizzle: is = gid>>9, g = gid&511 so
// the 8 sibling waves of one (bh,c) share gid%8 (one XCD L2) -> redundant
// r/v reads become L2 hits. Also stores cumw[t,i] for the parallel pass3.
__global__ __launch_bounds__(64)
void wkv7_pass1(const float* __restrict__ r, const float* __restrict__ w,
                const float* __restrict__ k, const float* __restrict__ v,
                float* __restrict__ y, float* __restrict__ cumw,
                float* __restrict__ Dend, float* __restrict__ E,
                int Bn, int Tn, int Hn)
{
    const int gid = blockIdx.x;            // is*512 + (bh*NC + c)
    const int is  = gid >> 9;              // 0..7
    const int g   = gid & 511;
    const int c   = g & (NC - 1);
    const int bh  = g >> 4;
    const int h   = bh % Hn;
    const int b   = bh / Hn;
    const int ln  = threadIdx.x;
    const int il  = ln >> 3;               // 0..7
    const int jq  = ln & 7;                // 0..7
    const int i   = is * 8 + il;
    const int C   = Hn * 64;
    const size_t cbase = (size_t)b * Tn * C + h * 64 + (size_t)(c * CL) * C;

    float st[8];
#pragma unroll
    for (int j = 0; j < 8; ++j) st[j] = 0.f;
    float cum = 1.f;

    float4 pv[4][2], pr[4][2];
    float pw[4], pk[4];

#define P1LOAD(s, T) {                                                        \
        const size_t o_ = cbase + (size_t)(T) * C;                            \
        pv[s][0] = *(const float4*)&v[o_ + jq * 8];                           \
        pv[s][1] = *(const float4*)&v[o_ + jq * 8 + 4];                       \
        pr[s][0] = *(const float4*)&r[o_ + jq * 8];                           \
        pr[s][1] = *(const float4*)&r[o_ + jq * 8 + 4];                       \
        pw[s] = w[o_ + i]; pk[s] = k[o_ + i]; }

    P1LOAD(0, 0) P1LOAD(1, 1) P1LOAD(2, 2) P1LOAD(3, 3)

    size_t yoff = cbase;
    for (int t = 0; t < CL; t += 4) {
#pragma unroll
        for (int s = 0; s < 4; ++s) {
            const float wi = pw[s];
            const float kf = pk[s];
            cum *= wi;
            float yi = 0.f;
#pragma unroll
            for (int q = 0; q < 2; ++q) {
                const float4 vf = pv[s][q];
                const float4 rf = pr[s][q];
                st[q * 4 + 0] = st[q * 4 + 0] * wi + kf * vf.x; yi += st[q * 4 + 0] * rf.x;
                st[q * 4 + 1] = st[q * 4 + 1] * wi + kf * vf.y; yi += st[q * 4 + 1] * rf.y;
                st[q * 4 + 2] = st[q * 4 + 2] * wi + kf * vf.z; yi += st[q * 4 + 2] * rf.z;
                st[q * 4 + 3] = st[q * 4 + 3] * wi + kf * vf.w; yi += st[q * 4 + 3] * rf.w;
            }
            yi += __shfl_xor(yi, 1);
            yi += __shfl_xor(yi, 2);
            yi += __shfl_xor(yi, 4);
            if (jq == 0) { y[yoff + i] = yi; cumw[yoff + i] = cum; }
            yoff += C;
            if (t + s + 4 < CL) P1LOAD(s, t + s + 4)
        }
    }
#undef P1LOAD

    if (jq == 0) Dend[((size_t)bh * NC + c) * 64 + i] = cum;
    const size_t eb = ((size_t)bh * NC + c) * 4096 + (size_t)i * 64 + jq * 8;
#pragma unroll
    for (int q = 0; q < 2; ++q)
        *(float4*)&E[eb + q * 4] = make_float4(st[q * 4 + 0], st[q * 4 + 1],
                                               st[q * 4 + 2], st[q * 4 + 3]);
}

// pass2: boundary states. grid = B*H, 256 thr. (unchanged)
__global__ __launch_bounds__(256)
void wkv7_pass2(const float* __restrict__ E, const float* __restrict__ Dend,
                float* __restrict__ S0, int Bn, int Tn, int Hn)
{
    const int bh = blockIdx.x;
    const int tid = threadIdx.x;
    const int i  = tid >> 2;
    const int jq = tid & 3;
    const size_t base = (size_t)bh * NC * 4096 + (size_t)i * 64 + jq * 16;

    float S[16];
#pragma unroll
    for (int q = 0; q < 16; ++q) S[q] = 0.f;

    for (int c = 0; c < NC; ++c) {
        const size_t idx = base + (size_t)c * 4096;
#pragma unroll
        for (int q = 0; q < 4; ++q)
            *(float4*)&S0[idx + q * 4] = make_float4(S[q * 4 + 0], S[q * 4 + 1],
                                                     S[q * 4 + 2], S[q * 4 + 3]);
        if (c + 1 < NC) {
            const float D = Dend[((size_t)bh * NC + c) * 64 + i];
#pragma unroll
            for (int q = 0; q < 4; ++q) {
                const float4 e = *(const float4*)&E[idx + q * 4];
                S[q * 4 + 0] = D * S[q * 4 + 0] + e.x;
                S[q * 4 + 1] = D * S[q * 4 + 1] + e.y;
                S[q * 4 + 2] = D * S[q * 4 + 2] + e.z;
                S[q * 4 + 3] = D * S[q * 4 + 3] + e.w;
            }
        }
    }
}

// pass3: ycorr[t,i] = cumw[t,i] * sum_j S0[i,j] r_t[j]. FULLY PARALLEL over t
// (cumw precomputed in pass1 -- no serial product). 8-way j-split, 512 thr,
// 4-deep register prefetch.
__global__ __launch_bounds__(512)
void wkv7_pass3(const float* __restrict__ r, const float* __restrict__ cumw,
                const float* __restrict__ S0, float* __restrict__ ycorr,
                int Bn, int Tn, int Hn)
{
    const int blk = blockIdx.x;
    const int c  = blk & (NC - 1);
    const int bh = blk >> 4;
    const int h  = bh % Hn, b = bh / Hn;
    const int tid = threadIdx.x;
    const int i  = tid >> 3;               // 0..63
    const int jq = tid & 7;                // 0..7
    const int C  = Hn * 64;
    const size_t cbase = ((size_t)b * Tn + c * CL) * C + h * 64;

    const size_t sb = ((size_t)bh * NC + c) * 4096 + (size_t)i * 64 + jq * 8;
    float4 s0[2];
#pragma unroll
    for (int q = 0; q < 2; ++q) s0[q] = *(const float4*)&S0[sb + q * 4];

    float4 pr[4][2]; float pcw[4];
#define P3LOAD(s, T) {                                                        \
        const size_t o_ = cbase + (size_t)(T) * C;                            \
        pr[s][0] = *(const float4*)&r[o_ + jq * 8];                           \
        pr[s][1] = *(const float4*)&r[o_ + jq * 8 + 4];                       \
        pcw[s] = cumw[o_ + i]; }

    P3LOAD(0, 0) P3LOAD(1, 1) P3LOAD(2, 2) P3LOAD(3, 3)

    size_t yoff = cbase;
    for (int t = 0; t < CL; t += 4) {
#pragma unroll
        for (int s = 0; s < 4; ++s) {
            float p = 0.f;
#pragma unroll
            for (int q = 0; q < 2; ++q) {
                const float4 rf = pr[s][q];
                p += s0[q].x * rf.x + s0[q].y * rf.y + s0[q].z * rf.z + s0[q].w * rf.w;
            }
            p += __shfl_xor(p, 1);
            p += __shfl_xor(p, 2);
            p += __shfl_xor(p, 4);
            if (jq == 0) ycorr[yoff + i] = pcw[s] * p;
            yoff += C;
            if (t + s + 4 < CL) P3LOAD(s, t + s + 4)
        }
    }
#undef P3LOAD
}

// ---- fused LN + rkv + gate (fp32 r/k/v, bf16 g) -> bf16 out ---------------
__global__ __launch_bounds__(256)
void ln_rkv_gate2(const float* __restrict__ y0, const float* __restrict__ yc,
                  const float* __restrict__ r, const float* __restrict__ k,
                  const float* __restrict__ v, const u16* __restrict__ g,
                  const float* __restrict__ r_k, const float* __restrict__ lng,
                  const float* __restrict__ lnb, u16* __restrict__ z, int C)
{
    const int m   = blockIdx.x;
    const int tid = threadIdx.x;
    const size_t base = (size_t)m * C;
    const int c = tid << 2;

    const float4 a  = *(const float4*)&y0[base + c];
    const float4 b4 = *(const float4*)&yc[base + c];
    float4 y4;
    y4.x = a.x + b4.x; y4.y = a.y + b4.y; y4.z = a.z + b4.z; y4.w = a.w + b4.w;

    float s  = y4.x + y4.y + y4.z + y4.w;
    float ss = y4.x * y4.x + y4.y * y4.y + y4.z * y4.z + y4.w * y4.w;
#pragma unroll
    for (int o = 1; o < 64; o <<= 1) { s += __shfl_xor(s, o); ss += __shfl_xor(ss, o); }
    __shared__ float red[2][4];
    const int wid = tid >> 6, lid = tid & 63;
    if (lid == 0) { red[0][wid] = s; red[1][wid] = ss; }
    __syncthreads();
    s  = red[0][0] + red[0][1] + red[0][2] + red[0][3];
    ss = red[1][0] + red[1][1] + red[1][2] + red[1][3];
    const float mean = s / (float)C;
    const float var  = ss / (float)C - mean * mean;
    const float inv  = rsqrtf(var + 1e-5f);

    const float4 r4  = *(const float4*)&r[base + c];
    const float4 k4  = *(const float4*)&k[base + c];
    const float4 rk4 = *(const float4*)&r_k[c];
    float p = r4.x * k4.x * rk4.x + r4.y * k4.y * rk4.y + r4.z * k4.z * rk4.z + r4.w * k4.w * rk4.w;
    p += __shfl_xor(p, 1); p += __shfl_xor(p, 2); p += __shfl_xor(p, 4); p += __shfl_xor(p, 8);

    const float4 v4 = *(const float4*)&v[base + c];
    const float4 g4 = b2f4(*(const ushort4*)&g[base + c]);
    const float4 lg = *(const float4*)&lng[c];
    const float4 lb = *(const float4*)&lnb[c];
    ushort4 res;
    res.x = f2b(((y4.x - mean) * inv * lg.x + lb.x + p * v4.x) * g4.x);
    res.y = f2b(((y4.y - mean) * inv * lg.y + lb.y + p * v4.y) * g4.y);
    res.z = f2b(((y4.z - mean) * inv * lg.z + lb.z + p * v4.z) * g4.z);
    res.w = f2b(((y4.w - mean) * inv * lg.w + lb.w + p * v4.w) * g4.w);
    *(ushort4*)&z[base + c] = res;
}

// ============================ FALLBACK (round-1 fp32) =======================

#define BM 64
#define BN 64
#define BK 32
enum { A_PLAIN = 0, A_MIX = 1 };
enum { EP_STORE = 0, EP_TANH = 1, EP_W = 2, EP_SIGMOID = 3, EP_AK = 4, EP_VBLEND = 5 };

template<int AMODE, int EPI>
__global__ __launch_bounds__(256)
void gemm_nt(const float* __restrict__ A, const float* __restrict__ tm,
             const float* __restrict__ W, float* __restrict__ O,
             const float* __restrict__ bias, const float* __restrict__ extra,
             int M, int K, int N, int Tdim)
{
    __shared__ float As[BK][BM + 4];
    __shared__ float Bs[BK][BN + 4];
    const int tid  = threadIdx.x;
    const int m0   = blockIdx.y * BM;
    const int n0   = blockIdx.x * BN;
    const int lrow = tid >> 3;
    const int lcol = (tid & 7) << 2;
    const int ty   = tid >> 4;
    const int tx   = tid & 15;
    float acc[4][4] = {{0.f}};

    for (int k0 = 0; k0 < K; k0 += BK) {
#pragma unroll
        for (int rr = 0; rr < 2; ++rr) {
            const int row = lrow + rr * 32;
            const int m   = m0 + row;
            float4 av;
            if (AMODE == A_MIX) {
                const float4 xc = *(const float4*)&A[(size_t)m * K + k0 + lcol];
                float4 xp = make_float4(0.f, 0.f, 0.f, 0.f);
                if ((m % Tdim) != 0)
                    xp = *(const float4*)&A[(size_t)(m - 1) * K + k0 + lcol];
                const float4 tc = *(const float4*)&tm[k0 + lcol];
                av.x = xc.x + (xp.x - xc.x) * tc.x;
                av.y = xc.y + (xp.y - xc.y) * tc.y;
                av.z = xc.z + (xp.z - xc.z) * tc.z;
                av.w = xc.w + (xp.w - xc.w) * tc.w;
            } else {
                av = *(const float4*)&A[(size_t)m * K + k0 + lcol];
            }
            As[lcol + 0][row] = av.x; As[lcol + 1][row] = av.y;
            As[lcol + 2][row] = av.z; As[lcol + 3][row] = av.w;
            const float4 bv = *(const float4*)&W[(size_t)(n0 + row) * K + k0 + lcol];
            Bs[lcol + 0][row] = bv.x; Bs[lcol + 1][row] = bv.y;
            Bs[lcol + 2][row] = bv.z; Bs[lcol + 3][row] = bv.w;
        }
        __syncthreads();
#pragma unroll
        for (int kk = 0; kk < BK; ++kk) {
            const float4 a4 = *(const float4*)&As[kk][ty << 2];
            const float4 b4 = *(const float4*)&Bs[kk][tx << 2];
            acc[0][0] += a4.x * b4.x; acc[0][1] += a4.x * b4.y; acc[0][2] += a4.x * b4.z; acc[0][3] += a4.x * b4.w;
            acc[1][0] += a4.y * b4.x; acc[1][1] += a4.y * b4.y; acc[1][2] += a4.y * b4.z; acc[1][3] += a4.y * b4.w;
            acc[2][0] += a4.z * b4.x; acc[2][1] += a4.z * b4.y; acc[2][2] += a4.z * b4.z; acc[2][3] += a4.z * b4.w;
            acc[3][0] += a4.w * b4.x; acc[3][1] += a4.w * b4.y; acc[3][2] += a4.w * b4.z; acc[3][3] += a4.w * b4.w;
        }
        __syncthreads();
    }

#pragma unroll
    for (int ii = 0; ii < 4; ++ii) {
        const int m = m0 + (ty << 2) + ii;
        const int n = n0 + (tx << 2);
        const size_t o = (size_t)m * N + n;
        const float a0v = acc[ii][0], a1v = acc[ii][1], a2v = acc[ii][2], a3v = acc[ii][3];
        float4 res;
        if (EPI == EP_STORE) {
            res = make_float4(a0v, a1v, a2v, a3v);
        } else if (EPI == EP_TANH) {
            res = make_float4(tanhf(a0v), tanhf(a1v), tanhf(a2v), tanhf(a3v));
        } else if (EPI == EP_SIGMOID) {
            res = make_float4(sigf(a0v), sigf(a1v), sigf(a2v), sigf(a3v));
        } else if (EPI == EP_W) {
            const float4 b = *(const float4*)&bias[n];
            res.x = expf(-0.606531f * sigf(b.x + a0v));
            res.y = expf(-0.606531f * sigf(b.y + a1v));
            res.z = expf(-0.606531f * sigf(b.z + a2v));
            res.w = expf(-0.606531f * sigf(b.w + a3v));
        } else if (EPI == EP_AK) {
            const float4 b  = *(const float4*)&bias[n];
            const float4 ka = *(const float4*)&extra[n];
            const float4 kv = *(const float4*)&O[o];
            res.x = kv.x * (1.f + (sigf(b.x + a0v) - 1.f) * ka.x);
            res.y = kv.y * (1.f + (sigf(b.y + a1v) - 1.f) * ka.y);
            res.z = kv.z * (1.f + (sigf(b.z + a2v) - 1.f) * ka.z);
            res.w = kv.w * (1.f + (sigf(b.w + a3v) - 1.f) * ka.w);
        } else {
            const float4 b  = *(const float4*)&bias[n];
            const float4 vf = *(const float4*)&extra[o];
            const float4 vv = *(const float4*)&O[o];
            float sx;
            sx = sigf(b.x + a0v); res.x = vv.x + (vf.x - vv.x) * sx;
            sx = sigf(b.y + a1v); res.y = vv.y + (vf.y - vv.y) * sx;
            sx = sigf(b.z + a2v); res.z = vv.z + (vf.z - vv.z) * sx;
            sx = sigf(b.w + a3v); res.w = vv.w + (vf.w - vv.w) * sx;
        }
        *(float4*)&O[o] = res;
    }
}

__global__ __launch_bounds__(64)
void wkv7_scan(const float* __restrict__ r, const float* __restrict__ w,
               const float* __restrict__ k, const float* __restrict__ v,
               float* __restrict__ y, int Bn, int Tn, int Hn)
{
    const int blk  = blockIdx.x;
    const int s    = blk & 3;
    const int h    = (blk >> 2) % Hn;
    const int b    = blk / (4 * Hn);
    const int lane = threadIdx.x;
    const int il   = lane >> 2;
    const int q    = lane & 3;
    const int i    = s * 16 + il;
    const int C    = Hn * 64;
    const size_t base = (size_t)b * Tn * C + h * 64;

    float st[16];
#pragma unroll
    for (int j = 0; j < 16; ++j) st[j] = 0.f;

    __shared__ float vs[4][64];
    __shared__ float rs[4][64];

    for (int t0 = 0; t0 < Tn; t0 += 4) {
        float vl[4], rl[4], wl[4], kl[4];
#pragma unroll
        for (int u = 0; u < 4; ++u) {
            const size_t off = base + (size_t)(t0 + u) * C;
            vl[u] = v[off + lane]; rl[u] = r[off + lane];
            wl[u] = w[off + i];    kl[u] = k[off + i];
        }
        __syncthreads();
#pragma unroll
        for (int u = 0; u < 4; ++u) { vs[u][lane] = vl[u]; rs[u][lane] = rl[u]; }
        __syncthreads();
#pragma unroll
        for (int u = 0; u < 4; ++u) {
            const float wi = wl[u], ki = kl[u];
            float yi = 0.f;
#pragma unroll
            for (int jg = 0; jg < 4; ++jg) {
                const float4 v4 = *(const float4*)&vs[u][q * 16 + jg * 4];
                const float4 r4 = *(const float4*)&rs[u][q * 16 + jg * 4];
                const int j = jg * 4;
                st[j + 0] = st[j + 0] * wi + ki * v4.x; yi += st[j + 0] * r4.x;
                st[j + 1] = st[j + 1] * wi + ki * v4.y; yi += st[j + 1] * r4.y;
                st[j + 2] = st[j + 2] * wi + ki * v4.z; yi += st[j + 2] * r4.z;
                st[j + 3] = st[j + 3] * wi + ki * v4.w; yi += st[j + 3] * r4.w;
            }
            yi += __shfl_xor(yi, 1);
            yi += __shfl_xor(yi, 2);
            if (q == 0) y[base + (size_t)(t0 + u) * C + i] = yi;
        }
    }
}

__global__ __launch_bounds__(256)
void ln_rkv_gate(const float* __restrict__ y, const float* __restrict__ r,
                 const float* __restrict__ k, const float* __restrict__ v,
                 const float* __restrict__ g, const float* __restrict__ r_k,
                 const float* __restrict__ lng, const float* __restrict__ lnb,
                 float* __restrict__ z, int C)
{
    const int m   = blockIdx.x;
    const int tid = threadIdx.x;
    const size_t base = (size_t)m * C;
    const int c = tid << 2;

    const float4 y4 = *(const float4*)&y[base + c];
    float s  = y4.x + y4.y + y4.z + y4.w;
    float ss = y4.x * y4.x + y4.y * y4.y + y4.z * y4.z + y4.w * y4.w;
#pragma unroll
    for (int o = 1; o < 64; o <<= 1) { s += __shfl_xor(s, o); ss += __shfl_xor(ss, o); }
    __shared__ float red[2][4];
    const int wid = tid >> 6, lid = tid & 63;
    if (lid == 0) { red[0][wid] = s; red[1][wid] = ss; }
    __syncthreads();
    s  = red[0][0] + red[0][1] + red[0][2] + red[0][3];
    ss = red[1][0] + red[1][1] + red[1][2] + red[1][3];
    const float mean = s / (float)C;
    const float var  = ss / (float)C - mean * mean;
    const float inv  = rsqrtf(var + 1e-5f);

    const float4 r4  = *(const float4*)&r[base + c];
    const float4 k4  = *(const float4*)&k[base + c];
    const float4 rk4 = *(const float4*)&r_k[c];
    float p = r4.x * k4.x * rk4.x + r4.y * k4.y * rk4.y + r4.z * k4.z * rk4.z + r4.w * k4.w * rk4.w;
    p += __shfl_xor(p, 1); p += __shfl_xor(p, 2); p += __shfl_xor(p, 4); p += __shfl_xor(p, 8);

    const float4 v4 = *(const float4*)&v[base + c];
    const float4 g4 = *(const float4*)&g[base + c];
    const float4 lg = *(const float4*)&lng[c];
    const float4 lb = *(const float4*)&lnb[c];
    float4 res;
    res.x = ((y4.x - mean) * inv * lg.x + lb.x + p * v4.x) * g4.x;
    res.y = ((y4.y - mean) * inv * lg.y + lb.y + p * v4.y) * g4.y;
    res.z = ((y4.z - mean) * inv * lg.z + lb.z + p * v4.z) * g4.z;
    res.w = ((y4.w - mean) * inv * lg.w + lb.w + p * v4.w) * g4.w;
    *(float4*)&z[base + c] = res;
}

// ============================ LAUNCH ========================================

extern "C" void kernel_launch(void* const* d_in, const int* in_sizes, int n_in,
                              void* d_out, int out_size, void* d_ws, size_t ws_size,
                              hipStream_t stream)
{
    const float* x    = (const float*)d_in[0];
    const float* vfst = (const float*)d_in[1];
    const float* Wr   = (const float*)d_in[2];
    const float* Wk   = (const float*)d_in[3];
    const float* Wv   = (const float*)d_in[4];
    const float* Wo   = (const float*)d_in[5];
    const float* Wg1  = (const float*)d_in[6];
    const float* Wg2  = (const float*)d_in[7];
    const float* W1   = (const float*)d_in[8];
    const float* W2   = (const float*)d_in[9];
    const float* A1   = (const float*)d_in[10];
    const float* A2   = (const float*)d_in[11];
    const float* V1   = (const float*)d_in[12];
    const float* V2   = (const float*)d_in[13];
    const float* tm_r = (const float*)d_in[14];
    const float* tm_w = (const float*)d_in[15];
    const float* tm_k = (const float*)d_in[16];
    const float* tm_v = (const float*)d_in[17];
    const float* tm_a = (const float*)d_in[18];
    const float* tm_g = (const float*)d_in[19];
    const float* w0   = (const float*)d_in[20];
    const float* a0   = (const float*)d_in[21];
    const float* v0   = (const float*)d_in[22];
    const float* k_a  = (const float*)d_in[24];
    const float* r_k  = (const float*)d_in[25];
    const float* ln_g = (const float*)d_in[26];
    const float* ln_b = (const float*)d_in[27];
    float* out = (float*)d_out;

    const int Bn = 2, Tn = 2048, C = 1024, Hh = 16;
    const int M = Bn * Tn, K = C, N = C;
    const size_t MBy = (size_t)1 << 20;
    const size_t NEED = 172 * MBy;

    if (ws_size >= NEED) {
        unsigned char* w8 = (unsigned char*)d_ws;
        // --- persistent weights ---
        u16* wb    = (u16*)(w8 + 0);            // 10 x 2MB bf16 weights
        u16* w1cat = (u16*)(w8 + 20 * MBy);     // 4MB [hi|hi]
        u16* w2cat = (u16*)(w8 + 24 * MBy);     // 4MB [hi|hi]
        // --- prep outputs (dead after s1) ---
        u16* axr   = (u16*)(w8 + 28 * MBy);
        u16* axk   = (u16*)(w8 + 36 * MBy);
        u16* axv   = (u16*)(w8 + 44 * MBy);
        u16* axa   = (u16*)(w8 + 52 * MBy);
        u16* axg   = (u16*)(w8 + 60 * MBy);
        u16* axw   = (u16*)(w8 + 68 * MBy);     // 16MB [hi|lo]
        // --- s1 outputs ---
        u16* btw   = (u16*)(w8 + 84 * MBy);     // 16MB [hi|lo], dead after s2
        u16* bt1a  = (u16*)(w8 + 100 * MBy);    // 8MB, dead after s2
        u16* bt1g  = (u16*)(w8 + 108 * MBy);    // 8MB, dead after s2
        u16* bt1v  = (u16*)(w8 + 116 * MBy);    // 8MB, dead after s2
        float* fr32 = (float*)(w8 + 124 * MBy); // 16MB fp32 r, live -> ln
        u16* bk    = (u16*)(w8 + 140 * MBy);    // 8MB bf16 k, dead after s2 j1
        u16* bv    = (u16*)(w8 + 148 * MBy);    // 8MB bf16 v, dead after s2 j3
        // --- s2 outputs (over dead ax*) ---
        float* bw   = (float*)(w8 + 28 * MBy);  // 16MB fp32 decay
        float* fk32 = (float*)(w8 + 44 * MBy);  // 16MB fp32 k (post-AK)
        float* fv32 = (float*)(w8 + 60 * MBy);  // 16MB fp32 v (post-blend)
        u16*  bg    = (u16*)(w8 + 76 * MBy);    // 8MB bf16 gate
        // --- scan buffers ---
        float* by   = (float*)(w8 + 84 * MBy);  // 16MB (over btw)
        float* byc  = (float*)(w8 + 100 * MBy); // 16MB (over bt1a/g)
        float* bE   = (float*)(w8 + 116 * MBy); // 8MB (over bt1v)
        float* cumw = (float*)(w8 + 140 * MBy); // 16MB (over dead bk+bv),
                                                //   pass1->pass3, dead after
        float* bDd  = (float*)(w8 + 156 * MBy); // 128KB (spare)
        float* bS0  = (float*)(w8 + 160 * MBy); // 8MB (spare)
        // --- ln output ---
        u16*  bz    = (u16*)(w8 + 140 * MBy);   // 8MB (over cumw, dead
                                                //   after pass3; ln > pass3)

        u16* wWr  = wb;              u16* wWk  = wb + (1u << 20);
        u16* wWv  = wb + (2u << 20); u16* wWo  = wb + (3u << 20);
        u16* wWg1 = wb + (4u << 20); u16* wWg2 = wb + (5u << 20);
        u16* wA1  = wb + (6u << 20); u16* wA2  = wb + (7u << 20);
        u16* wV1  = wb + (8u << 20); u16* wV2  = wb + (9u << 20);

        PrepArgs pa;
        pa.wp[0] = Wr;  pa.wp[1] = Wk;  pa.wp[2] = Wv;  pa.wp[3] = Wo;
        pa.wp[4] = Wg1; pa.wp[5] = Wg2; pa.wp[6] = A1;  pa.wp[7] = A2;
        pa.wp[8] = V1;  pa.wp[9] = V2;
        pa.wdst = wb;
        pa.W1 = W1; pa.W2 = W2; pa.c1 = w1cat; pa.c2 = w2cat;
        pa.x = x;
        pa.tmr = tm_r; pa.tmw = tm_w; pa.tmk = tm_k;
        pa.tmv = tm_v; pa.tma = tm_a; pa.tmg = tm_g;
        pa.axr = axr; pa.axk = axk; pa.axv = axv;
        pa.axa = axa; pa.axg = axg; pa.axw = axw;
        pa.T = Tn;
        prep_all<<<dim3(15360), dim3(256), 0, stream>>>(pa);

        // stage 1: 7 independent GEMMs (r -> fp32; k,v bf16 for s2 re-read)
        GemmBatch s1;
        s1.j[0] = { axw, w1cat, nullptr, btw,  nullptr, nullptr, 2048, FE_TANHCAT };
        s1.j[1] = { axr, wWr,   fr32,    nullptr, nullptr, nullptr, 1024, FE_F32 };
        s1.j[2] = { axk, wWk,   nullptr, bk,   nullptr, nullptr, 1024, FE_B16 };
        s1.j[3] = { axv, wWv,   nullptr, bv,   nullptr, nullptr, 1024, FE_B16 };
        s1.j[4] = { axa, wA1,   nullptr, bt1a, nullptr, nullptr, 1024, FE_B16 };
        s1.j[5] = { axg, wWg1,  nullptr, bt1g, nullptr, nullptr, 1024, FE_SIGB };
        s1.j[6] = { axv, wV1,   nullptr, bt1v, nullptr, nullptr, 1024, FE_B16 };
        mfma_batch8<<<dim3(7 * 64), dim3(512), 0, stream>>>(s1);

        // stage 2: 4 dependent GEMMs (k,v outputs fp32 for the scan)
        GemmBatch s2;
        s2.j[0] = { btw,  w2cat, bw,   nullptr, w0, nullptr, 2048, FE_W };
        s2.j[1] = { bt1a, wA2,   fk32, bk, a0, k_a,  1024, FE_AKF };
        s2.j[2] = { bt1g, wWg2,  nullptr, bg, nullptr, nullptr, 1024, FE_B16 };
        s2.j[3] = { bt1v, wV2,   fv32, bv, v0, vfst, 1024, FE_VBLENDF };
        s2.j[4] = s2.j[0]; s2.j[5] = s2.j[0]; s2.j[6] = s2.j[0];
        mfma_batch8<<<dim3(4 * 64), dim3(512), 0, stream>>>(s2);

        // chunked scan: pass1 with XCD-sibling swizzle + cumw store;
        // pass3 fully parallel (loads cumw).
        wkv7_pass1<<<dim3(Bn * Hh * NC * 8), dim3(64), 0, stream>>>(fr32, bw, fk32, fv32,
                                                                    by, cumw, bDd, bE,
                                                                    Bn, Tn, Hh);
        wkv7_pass2<<<dim3(Bn * Hh), dim3(256), 0, stream>>>(bE, bDd, bS0, Bn, Tn, Hh);
        wkv7_pass3<<<dim3(Bn * Hh * NC), dim3(512), 0, stream>>>(fr32, cumw, bS0, byc,
                                                                 Bn, Tn, Hh);

        // LN + rkv + gate -> bz (bf16)
        ln_rkv_gate2<<<dim3(M), dim3(256), 0, stream>>>(by, byc, fr32, fk32, fv32, bg,
                                                        r_k, ln_g, ln_b, bz, C);
        // out = z @ Wo^T  (single small GEMM: legacy 128^2 kernel, 256 blocks)
        GemmBatch s3;
        s3.j[0] = { bz, wWo, out, nullptr, nullptr, nullptr, 1024, FE_F32 };
        s3.j[1] = s3.j[0]; s3.j[2] = s3.j[0]; s3.j[3] = s3.j[0];
        s3.j[4] = s3.j[0]; s3.j[5] = s3.j[0]; s3.j[6] = s3.j[0];
        mfma_batch<<<dim3(256), dim3(256), 0, stream>>>(s3);
        return;
    }

    // -------- fallback: round-1 fp32 path (96MB ws) --------
    const size_t S = (size_t)M * C;
    float* ws = (float*)d_ws;
    float* fr = ws;
    float* fk = ws + S;
    float* fv = ws + 2 * S;
    float* fw = ws + 3 * S;
    float* fg = ws + 4 * S;
    float* ft = ws + 5 * S;
    float* fy = ft;

    dim3 grid(N / BN, M / BM);
    dim3 blk(256);

    gemm_nt<A_MIX, EP_STORE><<<grid, blk, 0, stream>>>(x, tm_r, Wr, fr, nullptr, nullptr, M, K, N, Tn);
    gemm_nt<A_MIX, EP_STORE><<<grid, blk, 0, stream>>>(x, tm_k, Wk, fk, nullptr, nullptr, M, K, N, Tn);
    gemm_nt<A_MIX, EP_STORE><<<grid, blk, 0, stream>>>(x, tm_v, Wv, fv, nullptr, nullptr, M, K, N, Tn);
    gemm_nt<A_MIX, EP_TANH><<<grid, blk, 0, stream>>>(x, tm_w, W1, ft, nullptr, nullptr, M, K, N, Tn);
    gemm_nt<A_PLAIN, EP_W><<<grid, blk, 0, stream>>>(ft, nullptr, W2, fw, w0, nullptr, M, K, N, Tn);
    gemm_nt<A_MIX, EP_STORE><<<grid, blk, 0, stream>>>(x, tm_a, A1, ft, nullptr, nullptr, M, K, N, Tn);
    gemm_nt<A_PLAIN, EP_AK><<<grid, blk, 0, stream>>>(ft, nullptr, A2, fk, a0, k_a, M, K, N, Tn);
    gemm_nt<A_MIX, EP_SIGMOID><<<grid, blk, 0, stream>>>(x, tm_g, Wg1, ft, nullptr, nullptr, M, K, N, Tn);
    gemm_nt<A_PLAIN, EP_STORE><<<grid, blk, 0, stream>>>(ft, nullptr, Wg2, fg, nullptr, nullptr, M, K, N, Tn);
    gemm_nt<A_MIX, EP_STORE><<<grid, blk, 0, stream>>>(x, tm_v, V1, ft, nullptr, nullptr, M, K, N, Tn);
    gemm_nt<A_PLAIN, EP_VBLEND><<<grid, blk, 0, stream>>>(ft, nullptr, V2, fv, v0, vfst, M, K, N, Tn);
    wkv7_scan<<<dim3(Bn * Hh * 4), dim3(64), 0, stream>>>(fr, fw, fk, fv, fy, Bn, Tn, Hh);
    ln_rkv_gate<<<dim3(M), dim3(256), 0, stream>>>(fy, fr, fk, fv, fg, r_k, ln_g, ln_b, fy, C);
    gemm_nt<A_PLAIN, EP_STORE><<<grid, blk, 0, stream>>>(fy, nullptr, Wo, out, nullptr, nullptr, M, K, N, Tn);
}

// Round 9
// 518.722 us; speedup vs baseline: 1.3158x; 1.3158x over previous
//
#include <hip/hip_runtime.h>
#include <hip/hip_bf16.h>
#include <cmath>

// ---------------------------------------------------------------------------
// RWKV-7 TimeMixing. B=2, T=2048, C=1024, H=16, N=64, M=4096.
// FAST path (ws >= 172MB):  [r6 base = best measured 520.7us, + scan-local]
//   - stages 1+2: 256x256-tile 8-wave phase-split MFMA GEMM (T2 swizzle +
//     counted vmcnt pipeline + setprio), global_load_lds staging, all-bf16
//     outputs (fp32 scan-input experiment of r7/r8 reverted: it inflated
//     write traffic and destabilized the GEMM dispatch, 520->613->682).
//   - chunked WKV7 scan (bf16 r/k/v, fp32 w): 8-way j-split + 4-deep reg
//     prefetch; pass1 XCD-sibling swizzle (is=gid>>9: the 8 redundant
//     i-split waves of one (bh,c) share blockIdx%8 -> one XCD L2, r/v
//     re-reads become L2 hits); pass1 stores cumw; pass3 fully parallel.
//   - fused LN + rkv + gate -> bf16, final Wo GEMM (legacy 128^2 kernel)
// FALLBACK: round-1 fp32 path, known-good.
// ---------------------------------------------------------------------------

typedef unsigned short u16;
typedef __attribute__((ext_vector_type(8))) short short8;   // 8 x bf16 frag
typedef __attribute__((ext_vector_type(4))) float f32x4;

#define NDIM 1024

__device__ __forceinline__ float sigf(float x) { return 1.f / (1.f + expf(-x)); }
__device__ __forceinline__ u16 f2b(float f) {
    union { float f; unsigned int u; } v; v.f = f;
    unsigned int r = (v.u + 0x7FFFu + ((v.u >> 16) & 1u)) >> 16;
    return (u16)r;
}
__device__ __forceinline__ float b2f(u16 b) {
    union { unsigned int u; float f; } v; v.u = ((unsigned int)b) << 16;
    return v.f;
}
__device__ __forceinline__ float4 b2f4(ushort4 u) {
    return make_float4(b2f(u.x), b2f(u.y), b2f(u.z), b2f(u.w));
}

#define GLD16(gp, lp)                                                         \
    __builtin_amdgcn_global_load_lds(                                         \
        (const __attribute__((address_space(1))) void*)(gp),                  \
        (__attribute__((address_space(3))) void*)(lp), 16, 0, 0)

// counted-vmcnt barrier
#define WAITB(n) do {                                                         \
    asm volatile("s_waitcnt vmcnt(" #n ")" ::: "memory");                     \
    __builtin_amdgcn_s_barrier();                                             \
    asm volatile("" ::: "memory"); } while (0)

// ============================ FAST PATH ====================================

// ---- fused prep: 10 weights->bf16 | W1,W2 cat | token-shift mixes --------
struct PrepArgs {
    const float* wp[10]; u16* wdst;
    const float* W1; const float* W2; u16* c1; u16* c2;
    const float* x;
    const float* tmr; const float* tmw; const float* tmk;
    const float* tmv; const float* tma; const float* tmg;
    u16 *axr, *axk, *axv, *axa, *axg, *axw;
    int T;
};

__global__ __launch_bounds__(256)
void prep_all(PrepArgs a)
{
    const int bid = blockIdx.x;
    const int tid = threadIdx.x;
    if (bid < 10240) {
        const int wi = bid >> 10;
        const int t  = (((bid & 1023) << 8) | tid) << 2;
        const float4 v = *(const float4*)&a.wp[wi][t];
        ushort4 o; o.x = f2b(v.x); o.y = f2b(v.y); o.z = f2b(v.z); o.w = f2b(v.w);
        *(ushort4*)&a.wdst[((size_t)wi << 20) + t] = o;
    } else if (bid < 11264) {
        const int t = ((bid - 10240) * 256 + tid) << 2;
        const int n = t >> 10, c = t & 1023;
        const size_t rb = (size_t)n * 2048 + c;
#pragma unroll
        for (int wsel = 0; wsel < 2; ++wsel) {
            const float* W = wsel ? a.W2 : a.W1;
            u16* dc = wsel ? a.c2 : a.c1;
            const float4 v = *(const float4*)&W[t];
            ushort4 hi;
            hi.x = f2b(v.x); hi.y = f2b(v.y); hi.z = f2b(v.z); hi.w = f2b(v.w);
            *(ushort4*)&dc[rb]        = hi;
            *(ushort4*)&dc[rb + 1024] = hi;
        }
    } else {
        const int t = ((bid - 11264) * 256 + tid) << 2;
        const int m = t >> 10, c = t & 1023;
        const float4 xc = *(const float4*)&a.x[t];
        float4 xp = make_float4(0.f, 0.f, 0.f, 0.f);
        if ((m % a.T) != 0) xp = *(const float4*)&a.x[t - 1024];
        const float4 d = make_float4(xp.x - xc.x, xp.y - xc.y, xp.z - xc.z, xp.w - xc.w);
#define MIX_STORE(tm, dstp)                                            \
    {   const float4 tc = *(const float4*)&tm[c];                      \
        ushort4 o;                                                     \
        o.x = f2b(xc.x + d.x * tc.x); o.y = f2b(xc.y + d.y * tc.y);    \
        o.z = f2b(xc.z + d.z * tc.z); o.w = f2b(xc.w + d.w * tc.w);    \
        *(ushort4*)&dstp[t] = o; }
        MIX_STORE(a.tmr, a.axr) MIX_STORE(a.tmk, a.axk) MIX_STORE(a.tmv, a.axv)
        MIX_STORE(a.tma, a.axa) MIX_STORE(a.tmg, a.axg)
#undef MIX_STORE
        {   // w path: [hi | lo]
            const float4 tc = *(const float4*)&a.tmw[c];
            float4 v = make_float4(xc.x + d.x * tc.x, xc.y + d.y * tc.y,
                                   xc.z + d.z * tc.z, xc.w + d.w * tc.w);
            ushort4 hi, lo;
            hi.x = f2b(v.x); lo.x = f2b(v.x - b2f(hi.x));
            hi.y = f2b(v.y); lo.y = f2b(v.y - b2f(hi.y));
            hi.z = f2b(v.z); lo.z = f2b(v.z - b2f(hi.z));
            hi.w = f2b(v.w); lo.w = f2b(v.w - b2f(hi.w));
            const size_t rb = (size_t)m * 2048 + c;
            *(ushort4*)&a.axw[rb]        = hi;
            *(ushort4*)&a.axw[rb + 1024] = lo;
        }
    }
}

// ---- shared job types -----------------------------------------------------
enum { FE_F32 = 0, FE_B16 = 1, FE_SIGB = 2, FE_TANHCAT = 3, FE_W = 4, FE_AK = 5, FE_VBLEND = 6 };

struct GemmJob {
    const u16* A; const u16* B; float* Of; u16* Ob;
    const float* bias; const float* extra; int K; int epi;
};
struct GemmBatch { GemmJob j[7]; };

// ===========================================================================
// 256x256-tile 8-wave phase-split NT-GEMM (bf16 MFMA). See r3 notes.
// ===========================================================================
__global__ __launch_bounds__(512, 1)
void mfma_batch8(GemmBatch batch)
{
    __shared__ __align__(16) u16 As[2][256 * 64];
    __shared__ __align__(16) u16 Bs[2][256 * 64];

    const GemmJob job = batch.j[blockIdx.x >> 6];
    const int t6 = blockIdx.x & 63;
    const int mt = ((t6 & 7) << 1) | ((t6 >> 3) & 1);   // 0..15
    const int nt = t6 >> 4;                              // 0..3
    const int m0 = mt << 8, n0 = nt << 8;
    const int K  = job.K;
    const u16* __restrict__ Ag = job.A;
    const u16* __restrict__ Bg = job.B;

    const int tid = threadIdx.x;
    const int wv  = tid >> 6;
    const int wm  = wv >> 2;
    const int wn  = wv & 3;
    const int ln  = tid & 63;
    const int fr  = ln & 15;
    const int fq  = ln >> 4;

    const int rowoff = tid >> 3;
    const int cgoff  = ((tid & 7) ^ (rowoff & 7)) << 3;
    const int wvb    = wv << 9;

    const int c0 = ((fq)     ^ (fr & 7)) << 3;
    const int c1 = ((4 + fq) ^ (fr & 7)) << 3;
    const int aOff0 = (wm * 16 + fr) * 64 + c0;
    const int aOff1 = (wm * 16 + fr) * 64 + c1;
    const int bBase = (wn * 64 + fr) * 64;

    f32x4 acc[8][4];
#pragma unroll
    for (int i = 0; i < 8; ++i)
#pragma unroll
        for (int j = 0; j < 4; ++j) {
            acc[i][j][0] = 0.f; acc[i][j][1] = 0.f; acc[i][j][2] = 0.f; acc[i][j][3] = 0.f;
        }

    auto stage = [&](const u16* __restrict__ G, int row0, u16* lp, int kc) {
        const u16* g0 = G + (size_t)(row0 + rowoff) * K + kc + cgoff;
        GLD16(g0, lp + wvb);
        GLD16(g0 + ((size_t)K << 6), lp + wvb + 4096);
    };

    stage(Bg, n0,       &Bs[0][0],    0);
    stage(Bg, n0 + 128, &Bs[0][8192], 0);
    stage(Ag, m0,       &As[0][0],    0);
    stage(Ag, m0 + 128, &As[0][8192], 0);

    short8 aL[4][2], aH[4][2], bA[2][2], bB[2][2];
    const int NT = K >> 6;
    int cur = 0;

    for (int kt = 0; kt < NT - 1; ++kt) {
        const int kn = (kt + 1) << 6;
        u16* An = &As[cur ^ 1][0];
        u16* Bn = &Bs[cur ^ 1][0];

        WAITB(2);
#pragma unroll
        for (int i = 0; i < 4; ++i) {
            aL[i][0] = *(const short8*)&As[cur][aOff0 + i * 2048];
            aL[i][1] = *(const short8*)&As[cur][aOff1 + i * 2048];
        }
#pragma unroll
        for (int j = 0; j < 2; ++j) {
            bA[j][0] = *(const short8*)&Bs[cur][bBase + j * 1024 + c0];
            bA[j][1] = *(const short8*)&Bs[cur][bBase + j * 1024 + c1];
        }
        stage(Bg, n0, Bn, kn);
        __builtin_amdgcn_s_setprio(1);
#pragma unroll
        for (int i = 0; i < 4; ++i)
#pragma unroll
            for (int j = 0; j < 2; ++j) {
                acc[i][j] = __builtin_amdgcn_mfma_f32_16x16x32_bf16(aL[i][0], bA[j][0], acc[i][j], 0, 0, 0);
                acc[i][j] = __builtin_amdgcn_mfma_f32_16x16x32_bf16(aL[i][1], bA[j][1], acc[i][j], 0, 0, 0);
            }
        __builtin_amdgcn_s_setprio(0);

#pragma unroll
        for (int j = 0; j < 2; ++j) {
            bB[j][0] = *(const short8*)&Bs[cur][bBase + (2 + j) * 1024 + c0];
            bB[j][1] = *(const short8*)&Bs[cur][bBase + (2 + j) * 1024 + c1];
        }
        stage(Bg, n0 + 128, Bn + 8192, kn);
        __builtin_amdgcn_s_setprio(1);
#pragma unroll
        for (int i = 0; i < 4; ++i)
#pragma unroll
            for (int j = 0; j < 2; ++j) {
                acc[i][2 + j] = __builtin_amdgcn_mfma_f32_16x16x32_bf16(aL[i][0], bB[j][0], acc[i][2 + j], 0, 0, 0);
                acc[i][2 + j] = __builtin_amdgcn_mfma_f32_16x16x32_bf16(aL[i][1], bB[j][1], acc[i][2 + j], 0, 0, 0);
            }
        __builtin_amdgcn_s_setprio(0);

        WAITB(4);
#pragma unroll
        for (int i = 0; i < 4; ++i) {
            aH[i][0] = *(const short8*)&As[cur][aOff0 + 8192 + i * 2048];
            aH[i][1] = *(const short8*)&As[cur][aOff1 + 8192 + i * 2048];
        }
        stage(Ag, m0, An, kn);
        __builtin_amdgcn_s_setprio(1);
#pragma unroll
        for (int i = 0; i < 4; ++i)
#pragma unroll
            for (int j = 0; j < 2; ++j) {
                acc[4 + i][j] = __builtin_amdgcn_mfma_f32_16x16x32_bf16(aH[i][0], bA[j][0], acc[4 + i][j], 0, 0, 0);
                acc[4 + i][j] = __builtin_amdgcn_mfma_f32_16x16x32_bf16(aH[i][1], bA[j][1], acc[4 + i][j], 0, 0, 0);
            }
        __builtin_amdgcn_s_setprio(0);

        stage(Ag, m0 + 128, An + 8192, kn);
        __builtin_amdgcn_s_setprio(1);
#pragma unroll
        for (int i = 0; i < 4; ++i)
#pragma unroll
            for (int j = 0; j < 2; ++j) {
                acc[4 + i][2 + j] = __builtin_amdgcn_mfma_f32_16x16x32_bf16(aH[i][0], bB[j][0], acc[4 + i][2 + j], 0, 0, 0);
                acc[4 + i][2 + j] = __builtin_amdgcn_mfma_f32_16x16x32_bf16(aH[i][1], bB[j][1], acc[4 + i][2 + j], 0, 0, 0);
            }
        __builtin_amdgcn_s_setprio(0);
        cur ^= 1;
    }

    WAITB(2);
#pragma unroll
    for (int i = 0; i < 4; ++i) {
        aL[i][0] = *(const short8*)&As[cur][aOff0 + i * 2048];
        aL[i][1] = *(const short8*)&As[cur][aOff1 + i * 2048];
    }
#pragma unroll
    for (int j = 0; j < 2; ++j) {
        bA[j][0] = *(const short8*)&Bs[cur][bBase + j * 1024 + c0];
        bA[j][1] = *(const short8*)&Bs[cur][bBase + j * 1024 + c1];
        bB[j][0] = *(const short8*)&Bs[cur][bBase + (2 + j) * 1024 + c0];
        bB[j][1] = *(const short8*)&Bs[cur][bBase + (2 + j) * 1024 + c1];
    }
    __builtin_amdgcn_s_setprio(1);
#pragma unroll
    for (int i = 0; i < 4; ++i)
#pragma unroll
        for (int j = 0; j < 2; ++j) {
            acc[i][j]     = __builtin_amdgcn_mfma_f32_16x16x32_bf16(aL[i][0], bA[j][0], acc[i][j], 0, 0, 0);
            acc[i][j]     = __builtin_amdgcn_mfma_f32_16x16x32_bf16(aL[i][1], bA[j][1], acc[i][j], 0, 0, 0);
            acc[i][2 + j] = __builtin_amdgcn_mfma_f32_16x16x32_bf16(aL[i][0], bB[j][0], acc[i][2 + j], 0, 0, 0);
            acc[i][2 + j] = __builtin_amdgcn_mfma_f32_16x16x32_bf16(aL[i][1], bB[j][1], acc[i][2 + j], 0, 0, 0);
        }
    __builtin_amdgcn_s_setprio(0);
    WAITB(0);
#pragma unroll
    for (int i = 0; i < 4; ++i) {
        aH[i][0] = *(const short8*)&As[cur][aOff0 + 8192 + i * 2048];
        aH[i][1] = *(const short8*)&As[cur][aOff1 + 8192 + i * 2048];
    }
    __builtin_amdgcn_s_setprio(1);
#pragma unroll
    for (int i = 0; i < 4; ++i)
#pragma unroll
        for (int j = 0; j < 2; ++j) {
            acc[4 + i][j]     = __builtin_amdgcn_mfma_f32_16x16x32_bf16(aH[i][0], bA[j][0], acc[4 + i][j], 0, 0, 0);
            acc[4 + i][j]     = __builtin_amdgcn_mfma_f32_16x16x32_bf16(aH[i][1], bA[j][1], acc[4 + i][j], 0, 0, 0);
            acc[4 + i][2 + j] = __builtin_amdgcn_mfma_f32_16x16x32_bf16(aH[i][0], bB[j][0], acc[4 + i][2 + j], 0, 0, 0);
            acc[4 + i][2 + j] = __builtin_amdgcn_mfma_f32_16x16x32_bf16(aH[i][1], bB[j][1], acc[4 + i][2 + j], 0, 0, 0);
        }
    __builtin_amdgcn_s_setprio(0);

    // ---- C write: epi switch hoisted OUT of the unrolled loops ----
    float* __restrict__ Of = job.Of;
    u16*   __restrict__ Ob = job.Ob;
    const float* bias  = job.bias;
    const float* extra = job.extra;
    const int epi = job.epi;

#define CWRITE(...)                                                           \
    _Pragma("unroll")                                                         \
    for (int i = 0; i < 8; ++i) {                                             \
        _Pragma("unroll")                                                     \
        for (int r = 0; r < 4; ++r) {                                         \
            const int m = m0 + i * 32 + wm * 16 + fq * 4 + r;                 \
            const size_t rowf = (size_t)m * NDIM;                             \
            _Pragma("unroll")                                                 \
            for (int j = 0; j < 4; ++j) {                                     \
                const int n = n0 + wn * 64 + j * 16 + fr;                     \
                const float val = acc[i][j][r];                               \
                __VA_ARGS__;                                                  \
            }                                                                 \
        }                                                                     \
    }

    switch (epi) {
    case FE_F32:
        CWRITE(Of[rowf + n] = val)
        break;
    case FE_B16:
        CWRITE(Ob[rowf + n] = f2b(val))
        break;
    case FE_SIGB:
        CWRITE(Ob[rowf + n] = f2b(sigf(val)))
        break;
    case FE_TANHCAT:
        CWRITE({
            const float tv = tanhf(val);
            const u16 hi = f2b(tv);
            const u16 lo = f2b(tv - b2f(hi));
            const size_t rc = (size_t)m * 2048;
            Ob[rc + n] = hi; Ob[rc + 1024 + n] = lo;
        })
        break;
    case FE_W:
        CWRITE(Of[rowf + n] = expf(-0.606531f * sigf(bias[n] + val)))
        break;
    case FE_AK:
        CWRITE({
            const float kv = b2f(Ob[rowf + n]);
            Ob[rowf + n] = f2b(kv * (1.f + (sigf(bias[n] + val) - 1.f) * extra[n]));
        })
        break;
    default: // FE_VBLEND
        CWRITE({
            const float vv = b2f(Ob[rowf + n]);
            const float s  = sigf(bias[n] + val);
            Ob[rowf + n] = f2b(vv + (extra[rowf + n] - vv) * s);
        })
        break;
    }
#undef CWRITE
}

// ---- legacy 128x128 MFMA kernel (kept for stage-3's small grid) ----------
#define TKt 32

__global__ __launch_bounds__(256)
void mfma_batch(GemmBatch batch)
{
    __shared__ u16 As[2][128 * 32];
    __shared__ u16 Bs[2][128 * 32];
    const GemmJob job = batch.j[blockIdx.x >> 8];
    const int bid = blockIdx.x & 255;
    const int m0 = (((bid & 7) << 2) + ((bid >> 3) & 3)) << 7;
    const int n0 = (bid >> 5) << 7;
    const int K  = job.K;
    const u16* __restrict__ Ag = job.A;
    const u16* __restrict__ Bg = job.B;

    const int t  = threadIdx.x;
    const int wv = t >> 6, ln = t & 63;
    const int wr = (wv >> 1) * 64;
    const int wc = (wv & 1) * 64;
    const int fr = ln & 15;
    const int fq = ln >> 4;
    const int lrow = ln >> 2;
    const int lcol = (ln & 3) << 3;

    f32x4 acc[4][4];
#pragma unroll
    for (int i = 0; i < 4; ++i)
#pragma unroll
        for (int j = 0; j < 4; ++j) {
            acc[i][j][0] = 0.f; acc[i][j][1] = 0.f; acc[i][j][2] = 0.f; acc[i][j][3] = 0.f;
        }

    const int slab0 = (wv << 4);
    const int slab1 = 64 + (wv << 4);

    auto issue = [&](int k0, int buf) {
        const size_t ga0 = (size_t)(m0 + slab0 + lrow) * K + k0 + lcol;
        const size_t ga1 = (size_t)(m0 + slab1 + lrow) * K + k0 + lcol;
        const size_t gb0 = (size_t)(n0 + slab0 + lrow) * K + k0 + lcol;
        const size_t gb1 = (size_t)(n0 + slab1 + lrow) * K + k0 + lcol;
        GLD16(Ag + ga0, &As[buf][slab0 * 32]);
        GLD16(Ag + ga1, &As[buf][slab1 * 32]);
        GLD16(Bg + gb0, &Bs[buf][slab0 * 32]);
        GLD16(Bg + gb1, &Bs[buf][slab1 * 32]);
    };

    issue(0, 0);
    const int NT = K / TKt;
    int cur = 0;
    for (int it = 0; it < NT; ++it) {
        __syncthreads();
        if (it + 1 < NT) issue((it + 1) * TKt, cur ^ 1);
        short8 af[4], bfr[4];
#pragma unroll
        for (int i = 0; i < 4; ++i) {
            af[i]  = *(const short8*)&As[cur][(wr + i * 16 + fr) * 32 + fq * 8];
            bfr[i] = *(const short8*)&Bs[cur][(wc + i * 16 + fr) * 32 + fq * 8];
        }
#pragma unroll
        for (int i = 0; i < 4; ++i)
#pragma unroll
            for (int j = 0; j < 4; ++j)
                acc[i][j] = __builtin_amdgcn_mfma_f32_16x16x32_bf16(af[i], bfr[j], acc[i][j], 0, 0, 0);
        cur ^= 1;
    }

    float* __restrict__ Of = job.Of;
    u16*   __restrict__ Ob = job.Ob;
    const float* bias  = job.bias;
    const float* extra = job.extra;
    const int epi = job.epi;

#pragma unroll
    for (int i = 0; i < 4; ++i) {
#pragma unroll
        for (int r = 0; r < 4; ++r) {
            const int m = m0 + wr + i * 16 + fq * 4 + r;
            const size_t rowf = (size_t)m * NDIM;
#pragma unroll
            for (int j = 0; j < 4; ++j) {
                const int n = n0 + wc + j * 16 + fr;
                const float val = acc[i][j][r];
                switch (epi) {
                case FE_F32:
                    Of[rowf + n] = val; break;
                case FE_B16:
                    Ob[rowf + n] = f2b(val); break;
                case FE_SIGB:
                    Ob[rowf + n] = f2b(sigf(val)); break;
                case FE_TANHCAT: {
                    const float tv = tanhf(val);
                    const u16 hi = f2b(tv);
                    const u16 lo = f2b(tv - b2f(hi));
                    const size_t rc = (size_t)m * 2048;
                    Ob[rc + n] = hi; Ob[rc + 1024 + n] = lo;
                    break; }
                case FE_W:
                    Of[rowf + n] = expf(-0.606531f * sigf(bias[n] + val)); break;
                case FE_AK: {
                    const float kv = b2f(Ob[rowf + n]);
                    Ob[rowf + n] = f2b(kv * (1.f + (sigf(bias[n] + val) - 1.f) * extra[n]));
                    break; }
                default: {
                    const float vv = b2f(Ob[rowf + n]);
                    const float s  = sigf(bias[n] + val);
                    Ob[rowf + n] = f2b(vv + (extra[rowf + n] - vv) * s);
                    break; }
                }
            }
        }
    }
}

// ---- WKV7 chunked scan ----------------------------------------------------
#define CL 128
#define NC 16

// pass1: zero-start scan per (b,h,chunk,i-split). 8-way j-split, 4-deep
// register prefetch. XCD-sibling swizzle: is = gid>>9 so the 8 sibling
// waves of one (bh,c) share gid%8 (one XCD L2) -> redundant r/v re-reads
// hit L2 not HBM. Stores cumw[t,i] for the parallel pass3.
__global__ __launch_bounds__(64)
void wkv7_pass1(const u16* __restrict__ r, const float* __restrict__ w,
                const u16* __restrict__ k, const u16* __restrict__ v,
                float* __restrict__ y, float* __restrict__ cumw,
                float* __restrict__ Dend, float* __restrict__ E,
                int Bn, int Tn, int Hn)
{
    const int gid = blockIdx.x;            // is*512 + (bh*NC + c)
    const int is  = gid >> 9;              // 0..7
    const int g   = gid & 511;
    const int c   = g & (NC - 1);
    const int bh  = g >> 4;
    const int h   = bh % Hn;
    const int b   = bh / Hn;
    const int ln  = threadIdx.x;
    const int il  = ln >> 3;               // 0..7
    const int jq  = ln & 7;                // 0..7
    const int i   = is * 8 + il;
    const int C   = Hn * 64;
    const size_t cbase = (size_t)b * Tn * C + h * 64 + (size_t)(c * CL) * C;

    float st[8];
#pragma unroll
    for (int j = 0; j < 8; ++j) st[j] = 0.f;
    float cum = 1.f;

    // 4-deep pipeline slots (all statically indexed)
    ushort4 pv[4][2], pr[4][2];
    float pw[4]; u16 pk[4];

#define P1LOAD(s, T) {                                                        \
        const size_t o_ = cbase + (size_t)(T) * C;                            \
        pv[s][0] = *(const ushort4*)&v[o_ + jq * 8];                          \
        pv[s][1] = *(const ushort4*)&v[o_ + jq * 8 + 4];                      \
        pr[s][0] = *(const ushort4*)&r[o_ + jq * 8];                          \
        pr[s][1] = *(const ushort4*)&r[o_ + jq * 8 + 4];                      \
        pw[s] = w[o_ + i]; pk[s] = k[o_ + i]; }

    P1LOAD(0, 0) P1LOAD(1, 1) P1LOAD(2, 2) P1LOAD(3, 3)

    size_t yoff = cbase;
    for (int t = 0; t < CL; t += 4) {
#pragma unroll
        for (int s = 0; s < 4; ++s) {
            const float wi = pw[s];
            const float kf = b2f(pk[s]);
            cum *= wi;
            float yi = 0.f;
#pragma unroll
            for (int q = 0; q < 2; ++q) {
                const float4 vf = b2f4(pv[s][q]);
                const float4 rf = b2f4(pr[s][q]);
                st[q * 4 + 0] = st[q * 4 + 0] * wi + kf * vf.x; yi += st[q * 4 + 0] * rf.x;
                st[q * 4 + 1] = st[q * 4 + 1] * wi + kf * vf.y; yi += st[q * 4 + 1] * rf.y;
                st[q * 4 + 2] = st[q * 4 + 2] * wi + kf * vf.z; yi += st[q * 4 + 2] * rf.z;
                st[q * 4 + 3] = st[q * 4 + 3] * wi + kf * vf.w; yi += st[q * 4 + 3] * rf.w;
            }
            yi += __shfl_xor(yi, 1);
            yi += __shfl_xor(yi, 2);
            yi += __shfl_xor(yi, 4);
            if (jq == 0) { y[yoff + i] = yi; cumw[yoff + i] = cum; }
            yoff += C;
            if (t + s + 4 < CL) P1LOAD(s, t + s + 4)
        }
    }
#undef P1LOAD

    if (jq == 0) Dend[((size_t)bh * NC + c) * 64 + i] = cum;
    const size_t eb = ((size_t)bh * NC + c) * 4096 + (size_t)i * 64 + jq * 8;
#pragma unroll
    for (int q = 0; q < 2; ++q)
        *(float4*)&E[eb + q * 4] = make_float4(st[q * 4 + 0], st[q * 4 + 1],
                                               st[q * 4 + 2], st[q * 4 + 3]);
}

// pass2: boundary states. grid = B*H, 256 thr. (unchanged)
__global__ __launch_bounds__(256)
void wkv7_pass2(const float* __restrict__ E, const float* __restrict__ Dend,
                float* __restrict__ S0, int Bn, int Tn, int Hn)
{
    const int bh = blockIdx.x;
    const int tid = threadIdx.x;
    const int i  = tid >> 2;
    const int jq = tid & 3;
    const size_t base = (size_t)bh * NC * 4096 + (size_t)i * 64 + jq * 16;

    float S[16];
#pragma unroll
    for (int q = 0; q < 16; ++q) S[q] = 0.f;

    for (int c = 0; c < NC; ++c) {
        const size_t idx = base + (size_t)c * 4096;
#pragma unroll
        for (int q = 0; q < 4; ++q)
            *(float4*)&S0[idx + q * 4] = make_float4(S[q * 4 + 0], S[q * 4 + 1],
                                                     S[q * 4 + 2], S[q * 4 + 3]);
        if (c + 1 < NC) {
            const float D = Dend[((size_t)bh * NC + c) * 64 + i];
#pragma unroll
            for (int q = 0; q < 4; ++q) {
                const float4 e = *(const float4*)&E[idx + q * 4];
                S[q * 4 + 0] = D * S[q * 4 + 0] + e.x;
                S[q * 4 + 1] = D * S[q * 4 + 1] + e.y;
                S[q * 4 + 2] = D * S[q * 4 + 2] + e.z;
                S[q * 4 + 3] = D * S[q * 4 + 3] + e.w;
            }
        }
    }
}

// pass3: ycorr[t,i] = cumw[t,i] * sum_j S0[i,j] r_t[j]. FULLY PARALLEL over t
// (cumw precomputed in pass1). 8-way j-split, 512 thr, 4-deep reg prefetch.
__global__ __launch_bounds__(512)
void wkv7_pass3(const u16* __restrict__ r, const float* __restrict__ cumw,
                const float* __restrict__ S0, float* __restrict__ ycorr,
                int Bn, int Tn, int Hn)
{
    const int blk = blockIdx.x;
    const int c  = blk & (NC - 1);
    const int bh = blk >> 4;
    const int h  = bh % Hn, b = bh / Hn;
    const int tid = threadIdx.x;
    const int i  = tid >> 3;               // 0..63
    const int jq = tid & 7;                // 0..7
    const int C  = Hn * 64;
    const size_t cbase = ((size_t)b * Tn + c * CL) * C + h * 64;

    const size_t sb = ((size_t)bh * NC + c) * 4096 + (size_t)i * 64 + jq * 8;
    float4 s0[2];
#pragma unroll
    for (int q = 0; q < 2; ++q) s0[q] = *(const float4*)&S0[sb + q * 4];

    ushort4 pr[4][2]; float pcw[4];
#define P3LOAD(s, T) {                                                        \
        const size_t o_ = cbase + (size_t)(T) * C;                            \
        pr[s][0] = *(const ushort4*)&r[o_ + jq * 8];                          \
        pr[s][1] = *(const ushort4*)&r[o_ + jq * 8 + 4];                      \
        pcw[s] = cumw[o_ + i]; }

    P3LOAD(0, 0) P3LOAD(1, 1) P3LOAD(2, 2) P3LOAD(3, 3)

    size_t yoff = cbase;
    for (int t = 0; t < CL; t += 4) {
#pragma unroll
        for (int s = 0; s < 4; ++s) {
            float p = 0.f;
#pragma unroll
            for (int q = 0; q < 2; ++q) {
                const float4 rf = b2f4(pr[s][q]);
                p += s0[q].x * rf.x + s0[q].y * rf.y + s0[q].z * rf.z + s0[q].w * rf.w;
            }
            p += __shfl_xor(p, 1);
            p += __shfl_xor(p, 2);
            p += __shfl_xor(p, 4);
            if (jq == 0) ycorr[yoff + i] = pcw[s] * p;
            yoff += C;
            if (t + s + 4 < CL) P3LOAD(s, t + s + 4)
        }
    }
#undef P3LOAD
}

__global__ __launch_bounds__(256)
void ln_rkv_gate2(const float* __restrict__ y0, const float* __restrict__ yc,
                  const u16* __restrict__ r, const u16* __restrict__ k,
                  const u16* __restrict__ v, const u16* __restrict__ g,
                  const float* __restrict__ r_k, const float* __restrict__ lng,
                  const float* __restrict__ lnb, u16* __restrict__ z, int C)
{
    const int m   = blockIdx.x;
    const int tid = threadIdx.x;
    const size_t base = (size_t)m * C;
    const int c = tid << 2;

    const float4 a  = *(const float4*)&y0[base + c];
    const float4 b4 = *(const float4*)&yc[base + c];
    float4 y4;
    y4.x = a.x + b4.x; y4.y = a.y + b4.y; y4.z = a.z + b4.z; y4.w = a.w + b4.w;

    float s  = y4.x + y4.y + y4.z + y4.w;
    float ss = y4.x * y4.x + y4.y * y4.y + y4.z * y4.z + y4.w * y4.w;
#pragma unroll
    for (int o = 1; o < 64; o <<= 1) { s += __shfl_xor(s, o); ss += __shfl_xor(ss, o); }
    __shared__ float red[2][4];
    const int wid = tid >> 6, lid = tid & 63;
    if (lid == 0) { red[0][wid] = s; red[1][wid] = ss; }
    __syncthreads();
    s  = red[0][0] + red[0][1] + red[0][2] + red[0][3];
    ss = red[1][0] + red[1][1] + red[1][2] + red[1][3];
    const float mean = s / (float)C;
    const float var  = ss / (float)C - mean * mean;
    const float inv  = rsqrtf(var + 1e-5f);

    const float4 r4  = b2f4(*(const ushort4*)&r[base + c]);
    const float4 k4  = b2f4(*(const ushort4*)&k[base + c]);
    const float4 rk4 = *(const float4*)&r_k[c];
    float p = r4.x * k4.x * rk4.x + r4.y * k4.y * rk4.y + r4.z * k4.z * rk4.z + r4.w * k4.w * rk4.w;
    p += __shfl_xor(p, 1); p += __shfl_xor(p, 2); p += __shfl_xor(p, 4); p += __shfl_xor(p, 8);

    const float4 v4 = b2f4(*(const ushort4*)&v[base + c]);
    const float4 g4 = b2f4(*(const ushort4*)&g[base + c]);
    const float4 lg = *(const float4*)&lng[c];
    const float4 lb = *(const float4*)&lnb[c];
    ushort4 res;
    res.x = f2b(((y4.x - mean) * inv * lg.x + lb.x + p * v4.x) * g4.x);
    res.y = f2b(((y4.y - mean) * inv * lg.y + lb.y + p * v4.y) * g4.y);
    res.z = f2b(((y4.z - mean) * inv * lg.z + lb.z + p * v4.z) * g4.z);
    res.w = f2b(((y4.w - mean) * inv * lg.w + lb.w + p * v4.w) * g4.w);
    *(ushort4*)&z[base + c] = res;
}

// ============================ FALLBACK (round-1 fp32) =======================

#define BM 64
#define BN 64
#define BK 32
enum { A_PLAIN = 0, A_MIX = 1 };
enum { EP_STORE = 0, EP_TANH = 1, EP_W = 2, EP_SIGMOID = 3, EP_AK = 4, EP_VBLEND = 5 };

template<int AMODE, int EPI>
__global__ __launch_bounds__(256)
void gemm_nt(const float* __restrict__ A, const float* __restrict__ tm,
             const float* __restrict__ W, float* __restrict__ O,
             const float* __restrict__ bias, const float* __restrict__ extra,
             int M, int K, int N, int Tdim)
{
    __shared__ float As[BK][BM + 4];
    __shared__ float Bs[BK][BN + 4];
    const int tid  = threadIdx.x;
    const int m0   = blockIdx.y * BM;
    const int n0   = blockIdx.x * BN;
    const int lrow = tid >> 3;
    const int lcol = (tid & 7) << 2;
    const int ty   = tid >> 4;
    const int tx   = tid & 15;
    float acc[4][4] = {{0.f}};

    for (int k0 = 0; k0 < K; k0 += BK) {
#pragma unroll
        for (int rr = 0; rr < 2; ++rr) {
            const int row = lrow + rr * 32;
            const int m   = m0 + row;
            float4 av;
            if (AMODE == A_MIX) {
                const float4 xc = *(const float4*)&A[(size_t)m * K + k0 + lcol];
                float4 xp = make_float4(0.f, 0.f, 0.f, 0.f);
                if ((m % Tdim) != 0)
                    xp = *(const float4*)&A[(size_t)(m - 1) * K + k0 + lcol];
                const float4 tc = *(const float4*)&tm[k0 + lcol];
                av.x = xc.x + (xp.x - xc.x) * tc.x;
                av.y = xc.y + (xp.y - xc.y) * tc.y;
                av.z = xc.z + (xp.z - xc.z) * tc.z;
                av.w = xc.w + (xp.w - xc.w) * tc.w;
            } else {
                av = *(const float4*)&A[(size_t)m * K + k0 + lcol];
            }
            As[lcol + 0][row] = av.x; As[lcol + 1][row] = av.y;
            As[lcol + 2][row] = av.z; As[lcol + 3][row] = av.w;
            const float4 bv = *(const float4*)&W[(size_t)(n0 + row) * K + k0 + lcol];
            Bs[lcol + 0][row] = bv.x; Bs[lcol + 1][row] = bv.y;
            Bs[lcol + 2][row] = bv.z; Bs[lcol + 3][row] = bv.w;
        }
        __syncthreads();
#pragma unroll
        for (int kk = 0; kk < BK; ++kk) {
            const float4 a4 = *(const float4*)&As[kk][ty << 2];
            const float4 b4 = *(const float4*)&Bs[kk][tx << 2];
            acc[0][0] += a4.x * b4.x; acc[0][1] += a4.x * b4.y; acc[0][2] += a4.x * b4.z; acc[0][3] += a4.x * b4.w;
            acc[1][0] += a4.y * b4.x; acc[1][1] += a4.y * b4.y; acc[1][2] += a4.y * b4.z; acc[1][3] += a4.y * b4.w;
            acc[2][0] += a4.z * b4.x; acc[2][1] += a4.z * b4.y; acc[2][2] += a4.z * b4.z; acc[2][3] += a4.z * b4.w;
            acc[3][0] += a4.w * b4.x; acc[3][1] += a4.w * b4.y; acc[3][2] += a4.w * b4.z; acc[3][3] += a4.w * b4.w;
        }
        __syncthreads();
    }

#pragma unroll
    for (int ii = 0; ii < 4; ++ii) {
        const int m = m0 + (ty << 2) + ii;
        const int n = n0 + (tx << 2);
        const size_t o = (size_t)m * N + n;
        const float a0v = acc[ii][0], a1v = acc[ii][1], a2v = acc[ii][2], a3v = acc[ii][3];
        float4 res;
        if (EPI == EP_STORE) {
            res = make_float4(a0v, a1v, a2v, a3v);
        } else if (EPI == EP_TANH) {
            res = make_float4(tanhf(a0v), tanhf(a1v), tanhf(a2v), tanhf(a3v));
        } else if (EPI == EP_SIGMOID) {
            res = make_float4(sigf(a0v), sigf(a1v), sigf(a2v), sigf(a3v));
        } else if (EPI == EP_W) {
            const float4 b = *(const float4*)&bias[n];
            res.x = expf(-0.606531f * sigf(b.x + a0v));
            res.y = expf(-0.606531f * sigf(b.y + a1v));
            res.z = expf(-0.606531f * sigf(b.z + a2v));
            res.w = expf(-0.606531f * sigf(b.w + a3v));
        } else if (EPI == EP_AK) {
            const float4 b  = *(const float4*)&bias[n];
            const float4 ka = *(const float4*)&extra[n];
            const float4 kv = *(const float4*)&O[o];
            res.x = kv.x * (1.f + (sigf(b.x + a0v) - 1.f) * ka.x);
            res.y = kv.y * (1.f + (sigf(b.y + a1v) - 1.f) * ka.y);
            res.z = kv.z * (1.f + (sigf(b.z + a2v) - 1.f) * ka.z);
            res.w = kv.w * (1.f + (sigf(b.w + a3v) - 1.f) * ka.w);
        } else {
            const float4 b  = *(const float4*)&bias[n];
            const float4 vf = *(const float4*)&extra[o];
            const float4 vv = *(const float4*)&O[o];
            float sx;
            sx = sigf(b.x + a0v); res.x = vv.x + (vf.x - vv.x) * sx;
            sx = sigf(b.y + a1v); res.y = vv.y + (vf.y - vv.y) * sx;
            sx = sigf(b.z + a2v); res.z = vv.z + (vf.z - vv.z) * sx;
            sx = sigf(b.w + a3v); res.w = vv.w + (vf.w - vv.w) * sx;
        }
        *(float4*)&O[o] = res;
    }
}

__global__ __launch_bounds__(64)
void wkv7_scan(const float* __restrict__ r, const float* __restrict__ w,
               const float* __restrict__ k, const float* __restrict__ v,
               float* __restrict__ y, int Bn, int Tn, int Hn)
{
    const int blk  = blockIdx.x;
    const int s    = blk & 3;
    const int h    = (blk >> 2) % Hn;
    const int b    = blk / (4 * Hn);
    const int lane = threadIdx.x;
    const int il   = lane >> 2;
    const int q    = lane & 3;
    const int i    = s * 16 + il;
    const int C    = Hn * 64;
    const size_t base = (size_t)b * Tn * C + h * 64;

    float st[16];
#pragma unroll
    for (int j = 0; j < 16; ++j) st[j] = 0.f;

    __shared__ float vs[4][64];
    __shared__ float rs[4][64];

    for (int t0 = 0; t0 < Tn; t0 += 4) {
        float vl[4], rl[4], wl[4], kl[4];
#pragma unroll
        for (int u = 0; u < 4; ++u) {
            const size_t off = base + (size_t)(t0 + u) * C;
            vl[u] = v[off + lane]; rl[u] = r[off + lane];
            wl[u] = w[off + i];    kl[u] = k[off + i];
        }
        __syncthreads();
#pragma unroll
        for (int u = 0; u < 4; ++u) { vs[u][lane] = vl[u]; rs[u][lane] = rl[u]; }
        __syncthreads();
#pragma unroll
        for (int u = 0; u < 4; ++u) {
            const float wi = wl[u], ki = kl[u];
            float yi = 0.f;
#pragma unroll
            for (int jg = 0; jg < 4; ++jg) {
                const float4 v4 = *(const float4*)&vs[u][q * 16 + jg * 4];
                const float4 r4 = *(const float4*)&rs[u][q * 16 + jg * 4];
                const int j = jg * 4;
                st[j + 0] = st[j + 0] * wi + ki * v4.x; yi += st[j + 0] * r4.x;
                st[j + 1] = st[j + 1] * wi + ki * v4.y; yi += st[j + 1] * r4.y;
                st[j + 2] = st[j + 2] * wi + ki * v4.z; yi += st[j + 2] * r4.z;
                st[j + 3] = st[j + 3] * wi + ki * v4.w; yi += st[j + 3] * r4.w;
            }
            yi += __shfl_xor(yi, 1);
            yi += __shfl_xor(yi, 2);
            if (q == 0) y[base + (size_t)(t0 + u) * C + i] = yi;
        }
    }
}

__global__ __launch_bounds__(256)
void ln_rkv_gate(const float* __restrict__ y, const float* __restrict__ r,
                 const float* __restrict__ k, const float* __restrict__ v,
                 const float* __restrict__ g, const float* __restrict__ r_k,
                 const float* __restrict__ lng, const float* __restrict__ lnb,
                 float* __restrict__ z, int C)
{
    const int m   = blockIdx.x;
    const int tid = threadIdx.x;
    const size_t base = (size_t)m * C;
    const int c = tid << 2;

    const float4 y4 = *(const float4*)&y[base + c];
    float s  = y4.x + y4.y + y4.z + y4.w;
    float ss = y4.x * y4.x + y4.y * y4.y + y4.z * y4.z + y4.w * y4.w;
#pragma unroll
    for (int o = 1; o < 64; o <<= 1) { s += __shfl_xor(s, o); ss += __shfl_xor(ss, o); }
    __shared__ float red[2][4];
    const int wid = tid >> 6, lid = tid & 63;
    if (lid == 0) { red[0][wid] = s; red[1][wid] = ss; }
    __syncthreads();
    s  = red[0][0] + red[0][1] + red[0][2] + red[0][3];
    ss = red[1][0] + red[1][1] + red[1][2] + red[1][3];
    const float mean = s / (float)C;
    const float var  = ss / (float)C - mean * mean;
    const float inv  = rsqrtf(var + 1e-5f);

    const float4 r4  = *(const float4*)&r[base + c];
    const float4 k4  = *(const float4*)&k[base + c];
    const float4 rk4 = *(const float4*)&r_k[c];
    float p = r4.x * k4.x * rk4.x + r4.y * k4.y * rk4.y + r4.z * k4.z * rk4.z + r4.w * k4.w * rk4.w;
    p += __shfl_xor(p, 1); p += __shfl_xor(p, 2); p += __shfl_xor(p, 4); p += __shfl_xor(p, 8);

    const float4 v4 = *(const float4*)&v[base + c];
    const float4 g4 = *(const float4*)&g[base + c];
    const float4 lg = *(const float4*)&lng[c];
    const float4 lb = *(const float4*)&lnb[c];
    float4 res;
    res.x = ((y4.x - mean) * inv * lg.x + lb.x + p * v4.x) * g4.x;
    res.y = ((y4.y - mean) * inv * lg.y + lb.y + p * v4.y) * g4.y;
    res.z = ((y4.z - mean) * inv * lg.z + lb.z + p * v4.z) * g4.z;
    res.w = ((y4.w - mean) * inv * lg.w + lb.w + p * v4.w) * g4.w;
    *(float4*)&z[base + c] = res;
}

// ============================ LAUNCH ========================================

extern "C" void kernel_launch(void* const* d_in, const int* in_sizes, int n_in,
                              void* d_out, int out_size, void* d_ws, size_t ws_size,
                              hipStream_t stream)
{
    const float* x    = (const float*)d_in[0];
    const float* vfst = (const float*)d_in[1];
    const float* Wr   = (const float*)d_in[2];
    const float* Wk   = (const float*)d_in[3];
    const float* Wv   = (const float*)d_in[4];
    const float* Wo   = (const float*)d_in[5];
    const float* Wg1  = (const float*)d_in[6];
    const float* Wg2  = (const float*)d_in[7];
    const float* W1   = (const float*)d_in[8];
    const float* W2   = (const float*)d_in[9];
    const float* A1   = (const float*)d_in[10];
    const float* A2   = (const float*)d_in[11];
    const float* V1   = (const float*)d_in[12];
    const float* V2   = (const float*)d_in[13];
    const float* tm_r = (const float*)d_in[14];
    const float* tm_w = (const float*)d_in[15];
    const float* tm_k = (const float*)d_in[16];
    const float* tm_v = (const float*)d_in[17];
    const float* tm_a = (const float*)d_in[18];
    const float* tm_g = (const float*)d_in[19];
    const float* w0   = (const float*)d_in[20];
    const float* a0   = (const float*)d_in[21];
    const float* v0   = (const float*)d_in[22];
    const float* k_a  = (const float*)d_in[24];
    const float* r_k  = (const float*)d_in[25];
    const float* ln_g = (const float*)d_in[26];
    const float* ln_b = (const float*)d_in[27];
    float* out = (float*)d_out;

    const int Bn = 2, Tn = 2048, C = 1024, Hh = 16;
    const int M = Bn * Tn, K = C, N = C;
    const size_t MBy = (size_t)1 << 20;
    const size_t NEED = 172 * MBy;

    if (ws_size >= NEED) {
        unsigned char* w8 = (unsigned char*)d_ws;
        u16* wb    = (u16*)(w8 + 0);            // 10 x 2MB bf16 weights
        u16* w1cat = (u16*)(w8 + 20 * MBy);     // 4MB [hi|hi]
        u16* w2cat = (u16*)(w8 + 24 * MBy);     // 4MB [hi|hi]
        u16* axr   = (u16*)(w8 + 28 * MBy);     // 8MB each
        u16* axk   = (u16*)(w8 + 36 * MBy);
        u16* axv   = (u16*)(w8 + 44 * MBy);
        u16* axa   = (u16*)(w8 + 52 * MBy);
        u16* axg   = (u16*)(w8 + 60 * MBy);
        u16* axw   = (u16*)(w8 + 68 * MBy);     // 16MB [hi|lo]
        u16* btw   = (u16*)(w8 + 84 * MBy);     // 16MB [hi|lo]
        u16* bt1a  = (u16*)(w8 + 100 * MBy);    // 8MB each
        u16* bt1g  = (u16*)(w8 + 108 * MBy);
        u16* bt1v  = (u16*)(w8 + 116 * MBy);
        u16* br    = (u16*)(w8 + 124 * MBy);    // bf16 r/k/v/g, 8MB each
        u16* bk    = (u16*)(w8 + 132 * MBy);
        u16* bv    = (u16*)(w8 + 140 * MBy);
        float* bw  = (float*)(w8 + 148 * MBy);  // fp32 decay, 16MB
        u16* bg    = (u16*)(w8 + 164 * MBy);
        // scan-phase aliases (ax*/btw/bt1* dead after GEMM stage 2)
        float* by   = (float*)(w8 + 28 * MBy);  // y zero-start, 16MB
        float* byc  = (float*)(w8 + 44 * MBy);  // ycorr, 16MB
        float* bE   = (float*)(w8 + 60 * MBy);  // end states, 8MB
        float* bDd  = (float*)(w8 + 68 * MBy);  // chunk-end decay, 128KB
        float* bS0  = (float*)(w8 + 70 * MBy);  // boundary states, 8MB
        float* cumw = (float*)(w8 + 100 * MBy); // 16MB (over bt1a+bt1g, dead
                                                //   after s2); pass1->pass3
        u16*  bz    = (u16*)(w8 + 84 * MBy);    // LN output, 8MB (over btw)

        u16* wWr  = wb;              u16* wWk  = wb + (1u << 20);
        u16* wWv  = wb + (2u << 20); u16* wWo  = wb + (3u << 20);
        u16* wWg1 = wb + (4u << 20); u16* wWg2 = wb + (5u << 20);
        u16* wA1  = wb + (6u << 20); u16* wA2  = wb + (7u << 20);
        u16* wV1  = wb + (8u << 20); u16* wV2  = wb + (9u << 20);

        PrepArgs pa;
        pa.wp[0] = Wr;  pa.wp[1] = Wk;  pa.wp[2] = Wv;  pa.wp[3] = Wo;
        pa.wp[4] = Wg1; pa.wp[5] = Wg2; pa.wp[6] = A1;  pa.wp[7] = A2;
        pa.wp[8] = V1;  pa.wp[9] = V2;
        pa.wdst = wb;
        pa.W1 = W1; pa.W2 = W2; pa.c1 = w1cat; pa.c2 = w2cat;
        pa.x = x;
        pa.tmr = tm_r; pa.tmw = tm_w; pa.tmk = tm_k;
        pa.tmv = tm_v; pa.tma = tm_a; pa.tmg = tm_g;
        pa.axr = axr; pa.axk = axk; pa.axv = axv;
        pa.axa = axa; pa.axg = axg; pa.axw = axw;
        pa.T = Tn;
        prep_all<<<dim3(15360), dim3(256), 0, stream>>>(pa);

        // stage 1: 7 independent GEMMs
        GemmBatch s1;
        s1.j[0] = { axw, w1cat, nullptr, btw,  nullptr, nullptr, 2048, FE_TANHCAT };
        s1.j[1] = { axr, wWr,   nullptr, br,   nullptr, nullptr, 1024, FE_B16 };
        s1.j[2] = { axk, wWk,   nullptr, bk,   nullptr, nullptr, 1024, FE_B16 };
        s1.j[3] = { axv, wWv,   nullptr, bv,   nullptr, nullptr, 1024, FE_B16 };
        s1.j[4] = { axa, wA1,   nullptr, bt1a, nullptr, nullptr, 1024, FE_B16 };
        s1.j[5] = { axg, wWg1,  nullptr, bt1g, nullptr, nullptr, 1024, FE_SIGB };
        s1.j[6] = { axv, wV1,   nullptr, bt1v, nullptr, nullptr, 1024, FE_B16 };
        mfma_batch8<<<dim3(7 * 64), dim3(512), 0, stream>>>(s1);

        // stage 2: 4 dependent GEMMs
        GemmBatch s2;
        s2.j[0] = { btw,  w2cat, bw,      nullptr, w0, nullptr, 2048, FE_W };
        s2.j[1] = { bt1a, wA2,   nullptr, bk,   a0, k_a,     1024, FE_AK };
        s2.j[2] = { bt1g, wWg2,  nullptr, bg,   nullptr, nullptr, 1024, FE_B16 };
        s2.j[3] = { bt1v, wV2,   nullptr, bv,   v0, vfst,    1024, FE_VBLEND };
        s2.j[4] = s2.j[0]; s2.j[5] = s2.j[0]; s2.j[6] = s2.j[0];
        mfma_batch8<<<dim3(4 * 64), dim3(512), 0, stream>>>(s2);

        // chunked scan: pass1 XCD-sibling swizzle + cumw store;
        // pass3 fully parallel (loads cumw).
        wkv7_pass1<<<dim3(Bn * Hh * NC * 8), dim3(64), 0, stream>>>(br, bw, bk, bv,
                                                                    by, cumw, bDd, bE,
                                                                    Bn, Tn, Hh);
        wkv7_pass2<<<dim3(Bn * Hh), dim3(256), 0, stream>>>(bE, bDd, bS0, Bn, Tn, Hh);
        wkv7_pass3<<<dim3(Bn * Hh * NC), dim3(512), 0, stream>>>(br, cumw, bS0, byc,
                                                                 Bn, Tn, Hh);

        // LN + rkv + gate -> bz (bf16)
        ln_rkv_gate2<<<dim3(M), dim3(256), 0, stream>>>(by, byc, br, bk, bv, bg,
                                                        r_k, ln_g, ln_b, bz, C);
        // out = z @ Wo^T  (single small GEMM: legacy 128^2 kernel, 256 blocks)
        GemmBatch s3;
        s3.j[0] = { bz, wWo, out, nullptr, nullptr, nullptr, 1024, FE_F32 };
        s3.j[1] = s3.j[0]; s3.j[2] = s3.j[0]; s3.j[3] = s3.j[0];
        s3.j[4] = s3.j[0]; s3.j[5] = s3.j[0]; s3.j[6] = s3.j[0];
        mfma_batch<<<dim3(256), dim3(256), 0, stream>>>(s3);
        return;
    }

    // -------- fallback: round-1 fp32 path (96MB ws) --------
    const size_t S = (size_t)M * C;
    float* ws = (float*)d_ws;
    float* fr = ws;
    float* fk = ws + S;
    float* fv = ws + 2 * S;
    float* fw = ws + 3 * S;
    float* fg = ws + 4 * S;
    float* ft = ws + 5 * S;
    float* fy = ft;

    dim3 grid(N / BN, M / BM);
    dim3 blk(256);

    gemm_nt<A_MIX, EP_STORE><<<grid, blk, 0, stream>>>(x, tm_r, Wr, fr, nullptr, nullptr, M, K, N, Tn);
    gemm_nt<A_MIX, EP_STORE><<<grid, blk, 0, stream>>>(x, tm_k, Wk, fk, nullptr, nullptr, M, K, N, Tn);
    gemm_nt<A_MIX, EP_STORE><<<grid, blk, 0, stream>>>(x, tm_v, Wv, fv, nullptr, nullptr, M, K, N, Tn);
    gemm_nt<A_MIX, EP_TANH><<<grid, blk, 0, stream>>>(x, tm_w, W1, ft, nullptr, nullptr, M, K, N, Tn);
    gemm_nt<A_PLAIN, EP_W><<<grid, blk, 0, stream>>>(ft, nullptr, W2, fw, w0, nullptr, M, K, N, Tn);
    gemm_nt<A_MIX, EP_STORE><<<grid, blk, 0, stream>>>(x, tm_a, A1, ft, nullptr, nullptr, M, K, N, Tn);
    gemm_nt<A_PLAIN, EP_AK><<<grid, blk, 0, stream>>>(ft, nullptr, A2, fk, a0, k_a, M, K, N, Tn);
    gemm_nt<A_MIX, EP_SIGMOID><<<grid, blk, 0, stream>>>(x, tm_g, Wg1, ft, nullptr, nullptr, M, K, N, Tn);
    gemm_nt<A_PLAIN, EP_STORE><<<grid, blk, 0, stream>>>(ft, nullptr, Wg2, fg, nullptr, nullptr, M, K, N, Tn);
    gemm_nt<A_MIX, EP_STORE><<<grid, blk, 0, stream>>>(x, tm_v, V1, ft, nullptr, nullptr, M, K, N, Tn);
    gemm_nt<A_PLAIN, EP_VBLEND><<<grid, blk, 0, stream>>>(ft, nullptr, V2, fv, v0, vfst, M, K, N, Tn);
    wkv7_scan<<<dim3(Bn * Hh * 4), dim3(64), 0, stream>>>(fr, fw, fk, fv, fy, Bn, Tn, Hh);
    ln_rkv_gate<<<dim3(M), dim3(256), 0, stream>>>(fy, fr, fk, fv, fg, r_k, ln_g, ln_b, fy, C);
    gemm_nt<A_PLAIN, EP_STORE><<<grid, blk, 0, stream>>>(fy, nullptr, Wo, out, nullptr, nullptr, M, K, N, Tn);
}